// Round 8
// baseline (533.121 us; speedup 1.0000x reference)
//
#include <hip/hip_runtime.h>

typedef unsigned int  u32;
typedef unsigned long long u64;
typedef unsigned short u16;
typedef __attribute__((ext_vector_type(8))) _Float16 h8;   // MFMA A/B frag: 8 fp16 = 4 VGPR
typedef __attribute__((ext_vector_type(2))) _Float16 h2;   // packed fp16 pair
typedef __attribute__((ext_vector_type(4))) float    f4;   // MFMA C/D frag

#define RS    136    // X row stride (fp16): 272B rows, 16B-aligned, 2-way banks
#define PRS   40     // row stride for vde weights (K=18 padded to 32, stored 40)
#define PIXB  256    // pixels per block (4 waves x 64 pixels)
#define WOFF  5120   // vde region size (halves)
#define WT    16384  // one unpadded swizzled weight tile [128][128] (halves)
#define MFMA16 __builtin_amdgcn_mfma_f32_16x16x32_f16

__device__ __forceinline__ u16 f2h(float f) {
  _Float16 h = (_Float16)f;
  return __builtin_bit_cast(u16, h);
}
__device__ __forceinline__ u32 pkrtz(float a, float b) {
  return __builtin_bit_cast(u32, __builtin_amdgcn_cvt_pkrtz(a, b));
}
__device__ __forceinline__ u32 pkmul(u32 a, u32 b) {   // v_pk_mul_f16
  h2 r = __builtin_bit_cast(h2, a) * __builtin_bit_cast(h2, b);
  return __builtin_bit_cast(u32, r);
}
__device__ __forceinline__ u32 pkmax0(u32 a) {         // v_pk_max_f16 vs 0
  h2 z = {(_Float16)0.f, (_Float16)0.f};
  h2 r = __builtin_elementwise_max(__builtin_bit_cast(h2, a), z);
  return __builtin_bit_cast(u32, r);
}

// ---------------------------------------------------------------------------
// Prep: fp16 weights, transposed to [out][in].
// ws (halves): [0,5120) vdeT [128][40] (k<18 valid)
//   [5120 + j*16384), j=0..11: [128][128] tiles, XOR-SWIZZLED within rows:
//   element (n,k) stored at column k ^ ((n&7)<<3)  (involution; makes the
//   later ds_read_b128 A-frag reads bank-conflict-free after a LINEAR DMA).
//   j: 0..2 vh, 3..8 hid, 9 headW0, 10 headW1, 11 headW2 (n>=4 zero)
// ---------------------------------------------------------------------------
__global__ __launch_bounds__(256) void rc_prep(
    const float* __restrict__ vde_W, const float* __restrict__ vh_W,
    const float* __restrict__ hid_W, const float* __restrict__ head_W0,
    const float* __restrict__ head_W1, const float* __restrict__ head_W2,
    u16* __restrict__ ws)
{
  const int TOT = WOFF + 12 * WT;   // 201728
  int i = blockIdx.x * 256 + threadIdx.x;
  if (i >= TOT) return;
  float val = 0.f;
  if (i < WOFF) {
    int n = i / PRS, k = i - n * PRS;
    if (k < 18) val = vde_W[k * 128 + n];
  } else {
    int t = i - WOFF;
    int j = t >> 14;
    int rr = t & 16383;
    int n = rr >> 7, kq = rr & 127;
    int k = kq ^ ((n & 7) << 3);          // element stored at this position
    if (j < 3)        val = vh_W[j * 16384 + k * 128 + n];
    else if (j < 9)   val = hid_W[(j - 3) * 16384 + k * 128 + n];
    else if (j == 9)  val = head_W0[k * 128 + n];
    else if (j == 10) val = head_W1[k * 128 + n];
    else              val = (n < 4) ? head_W2[k * 4 + n] : 0.f;
  }
  ws[i] = f2h(val);
}

// ---------------------------------------------------------------------------
// STAGE: DMA one 32KB weight tile global->LDS (linear; source pre-swizzled).
// Per wave: 8 x global_load_lds(16B). LDS dest = uniform base + lane*16.
// ---------------------------------------------------------------------------
#define STAGE(WBUF, j) do {                                                   \
  const u16* _s = ws + WOFF + (j) * WT + w * 4096 + lane * 8;                 \
  _Pragma("unroll")                                                           \
  for (int _it = 0; _it < 8; ++_it)                                           \
    __builtin_amdgcn_global_load_lds(                                         \
        (const __attribute__((address_space(1))) void*)(_s + _it * 512),      \
        (__attribute__((address_space(3))) void*)&WBUF[w * 4096 + _it * 512], \
        16, 0, 0);                                                            \
} while (0)

// compute output-tile NT (4 pixel-tiles) with weights from LDS buffer WBUF.
// A-frag read applies the XOR swizzle; bias from BL (f32-exact C-init);
// epilogue: cvt_pkrtz -> packed relu -> [capture | pk_mul] -> ds_write_b64.
#define COMPUTE_NT(WBUF, NT) do {                                             \
  h8 Aw[4];                                                                   \
  _Pragma("unroll")                                                           \
  for (int ks = 0; ks < 4; ++ks)                                              \
    Aw[ks] = *(const h8*)&WBUF[((NT) * 16 + r) * 128 + ((ks * 32 + g * 8) ^ rsw)]; \
  f4 bini = *(const f4*)&BL[blb + (NT) * 16 + 4 * g];                         \
  f4 ac[4] = {bini, bini, bini, bini};                                        \
  _Pragma("unroll")                                                           \
  for (int ks = 0; ks < 4; ++ks) {                                            \
    ac[0] = MFMA16(Aw[ks], x[0][ks], ac[0], 0, 0, 0);                         \
    ac[1] = MFMA16(Aw[ks], x[1][ks], ac[1], 0, 0, 0);                         \
    ac[2] = MFMA16(Aw[ks], x[2][ks], ac[2], 0, 0, 0);                         \
    ac[3] = MFMA16(Aw[ks], x[3][ks], ac[3], 0, 0, 0);                         \
  }                                                                           \
  const int col = (NT) * 16 + 4 * g;                                          \
  _Pragma("unroll")                                                           \
  for (int t = 0; t < 4; ++t) {                                               \
    u32 lo = pkmax0(pkrtz(ac[t][0], ac[t][1]));                               \
    u32 hi = pkmax0(pkrtz(ac[t][2], ac[t][3]));                               \
    if (mode == 1) {                       /* capture vh (packed) */          \
      vhp[t][NT][0] = lo; vhp[t][NT][1] = hi;                                 \
    } else {                                                                  \
      if (mode == 2) {                     /* h = relu(out) * vh */           \
        lo = pkmul(lo, vhp[t][NT][0]);                                        \
        hi = pkmul(hi, vhp[t][NT][1]);                                        \
      }                                                                       \
      *(uint2*)&X[xr[t] + col] = make_uint2(lo, hi);                          \
    }                                                                         \
  }                                                                           \
} while (0)

// one full 128x128 layer: issue next tile's DMA, compute from current LDS
// tile, optional gather, then __syncthreads (drains DMA = staging fence).
#define LAYER(LI, CURB, NXTB) do {                                            \
  const int li   = (LI);                                                      \
  const int blb  = (li + 1) * 128;                                            \
  const int mode = (li == 2) ? 1 : (li == 5) ? 2 : 0;                         \
  STAGE(NXTB, li + 1);                                                        \
  h8 x[4][4];                                                                 \
  _Pragma("unroll")                                                           \
  for (int t = 0; t < 4; ++t)                                                 \
    _Pragma("unroll")                                                         \
    for (int ks = 0; ks < 4; ++ks)                                            \
      x[t][ks] = *(const h8*)&X[xr[t] + ks * 32 + g * 8];                     \
  COMPUTE_NT(CURB, 0); COMPUTE_NT(CURB, 1);                                   \
  COMPUTE_NT(CURB, 2); COMPUTE_NT(CURB, 3);                                   \
  COMPUTE_NT(CURB, 4); COMPUTE_NT(CURB, 5);                                   \
  COMPUTE_NT(CURB, 6); COMPUTE_NT(CURB, 7);                                   \
  if (li == 2) do_gather();                                                   \
  __syncthreads();                                                            \
} while (0)

// ---------------------------------------------------------------------------
// Main fused kernel — LDS-staged weights, DMA double-buffer (WLA/WLB as
// separate arrays so alias analysis never stalls compute reads on the DMA).
// 1 block/CU (138.5 KB LDS), 4 waves x 64 px; steady-state loop is pure
// LDS+MFMA+VALU — no VMEM in the critical path.
// ---------------------------------------------------------------------------
__global__ __launch_bounds__(256, 1) void rc_main(
    const int*   __restrict__ vert,  const float* __restrict__ bary,
    const float* __restrict__ view,  const float* __restrict__ emb,
    const float* __restrict__ vde_b, const float* __restrict__ vh_b,
    const float* __restrict__ hid_b, const float* __restrict__ head_b0,
    const float* __restrict__ head_b1, const float* __restrict__ head_b2,
    const u16*   __restrict__ ws,    float* __restrict__ out)
{
  __shared__ __align__(16) u16   X[PIXB * RS];   // 69632 B activations
  __shared__ __align__(16) u16   WLA[WT];        // 32768 B weight tile (even)
  __shared__ __align__(16) u16   WLB[WT];        // 32768 B weight tile (odd)
  __shared__ __align__(16) float BL[1664];       // 6656 B: all biases

  const int tid  = threadIdx.x;
  const int lane = tid & 63;
  const int w    = tid >> 6;
  const int r    = lane & 15;       // pixel-within-tile; A row
  const int g    = lane >> 4;       // k-group; D row group
  const int pb   = w * 64;          // wave's first pixel row (64 px/wave)
  const int rsw  = (r & 7) << 3;    // weight-read XOR swizzle (fp16 units)
  const size_t bpix = (size_t)blockIdx.x * PIXB;

  // ---- cooperative bias load into LDS
  for (int i = tid; i < 1664; i += 256) {
    float v;
    if      (i < 128)  v = vde_b[i];
    else if (i < 512)  v = vh_b[i - 128];
    else if (i < 1280) v = hid_b[i - 512];
    else if (i < 1408) v = head_b0[i - 1280];
    else if (i < 1536) v = head_b1[i - 1408];
    else if (i < 1540) v = head_b2[i - 1536];
    else               v = 0.f;
    BL[i] = v;
  }

  // ---- PE: every lane computes its pixel's sin/cos encoding into X[row][0..32)
  {
    const int p = pb + lane;
    const float* vd = view + (bpix + p) * 3;
    const float SG0 = 6.28318530718f;   // 2pi / 0.9^0
    const float SG1 = 6.50777324f;      // 2pi / 0.9^(1/3)
    const float SG2 = 6.74038866f;      // 2pi / 0.9^(2/3)
    u32 pw[16];
#pragma unroll
    for (int i = 0; i < 3; ++i) {
      float x = vd[i];
      float s0 = __sinf(x * SG0), c0 = __cosf(x * SG0);
      float s1 = __sinf(x * SG1), c1 = __cosf(x * SG1);
      float s2 = __sinf(x * SG2), c2 = __cosf(x * SG2);
      pw[i * 3 + 0] = (u32)f2h(s0) | ((u32)f2h(s1) << 16);
      pw[i * 3 + 1] = (u32)f2h(s2) | ((u32)f2h(c0) << 16);
      pw[i * 3 + 2] = (u32)f2h(c1) | ((u32)f2h(c2) << 16);
    }
#pragma unroll
    for (int q = 9; q < 16; ++q) pw[q] = 0u;   // zero-pad k = 18..31
    uint4* dst = (uint4*)&X[p * RS];
#pragma unroll
    for (int q = 0; q < 4; ++q)
      dst[q] = make_uint4(pw[4*q], pw[4*q+1], pw[4*q+2], pw[4*q+3]);
  }
  __syncthreads();

  const int xr[4] = { (pb +      r) * RS, (pb + 16 + r) * RS,
                      (pb + 32 + r) * RS, (pb + 48 + r) * RS };

  // ---- gather closure (used at li==2): embedding + renorm + bary -> X
  auto do_gather = [&]() {
#pragma unroll 4
    for (int i = 0; i < 16; ++i) {
      int p = pb + g * 16 + i;               // 16-lane group g handles 16 pixels
      size_t gp = bpix + p;
      const int*   vi = vert + gp * 3;
      const float* by = bary + gp * 3;
      f4 va = {0.f,0.f,0.f,0.f}, vb = {0.f,0.f,0.f,0.f};
#pragma unroll
      for (int vt = 0; vt < 3; ++vt) {
        int id = vi[vt] + 1;
        const float* row = emb + (size_t)id * 128 + r * 8;  // lane r: 8 chans
        f4 e0 = *(const f4*)row;
        f4 e1 = *(const f4*)(row + 4);
        float ss = e0[0]*e0[0] + e0[1]*e0[1] + e0[2]*e0[2] + e0[3]*e0[3]
                 + e1[0]*e1[0] + e1[1]*e1[1] + e1[2]*e1[2] + e1[3]*e1[3];
        ss += __shfl_xor(ss, 1);             // reduce within the 16-lane group
        ss += __shfl_xor(ss, 2);
        ss += __shfl_xor(ss, 4);
        ss += __shfl_xor(ss, 8);
        float nrm = sqrtf(ss);
        float sc  = (nrm > 1.f) ? (1.f / (nrm + 1e-7f)) : 1.f;  // torch max_norm
        float wt  = by[vt] * sc;
#pragma unroll
        for (int j = 0; j < 4; ++j) { va[j] += wt * e0[j]; vb[j] += wt * e1[j]; }
      }
      h8 o;
#pragma unroll
      for (int j = 0; j < 4; ++j) { o[j] = (_Float16)va[j]; o[j+4] = (_Float16)vb[j]; }
      *(h8*)&X[p * RS + r * 8] = o;
    }
  };

  // ---- L0: vde (K=18 padded to 32) from global; stage layer-0 tile meanwhile
  STAGE(WLA, 0);
  {
    h8 Av[8];
#pragma unroll
    for (int nt = 0; nt < 8; ++nt)
      Av[nt] = *(const h8*)&ws[(nt * 16 + r) * PRS + g * 8];
    h8 pe[4];
#pragma unroll
    for (int t = 0; t < 4; ++t) pe[t] = *(const h8*)&X[xr[t] + g * 8];
#pragma unroll
    for (int nt = 0; nt < 8; ++nt) {
      f4 bini = *(const f4*)&BL[nt * 16 + 4 * g];
      const int col = nt * 16 + 4 * g;
#pragma unroll
      for (int t = 0; t < 4; ++t) {
        f4 acc = MFMA16(Av[nt], pe[t], bini, 0, 0, 0);
        *(uint2*)&X[xr[t] + col] =          // no relu on vde output
          make_uint2(pkrtz(acc[0], acc[1]), pkrtz(acc[2], acc[3]));
      }
    }
  }
  __syncthreads();   // WLA tile landed (DMA had the whole vde phase)

  // ---- 11 full 128x128 layers: even layers read WLA/stage WLB, odd converse
  u32 vhp[4][8][2];   // captured vh: set at li==2, used at li==5
#pragma unroll 1
  for (int lp = 0; lp < 5; ++lp) {
    LAYER(2 * lp,     WLA, WLB);
    LAYER(2 * lp + 1, WLB, WLA);
  }
  LAYER(10, WLA, WLB);   // stages j=11 (head tile) into WLB

  // ---- head_W2 (128 -> 4) + head_b2 from WLB
  {
    h8 x[4][4];
#pragma unroll
    for (int t = 0; t < 4; ++t)
#pragma unroll
      for (int ks = 0; ks < 4; ++ks)
        x[t][ks] = *(const h8*)&X[xr[t] + ks * 32 + g * 8];
    f4 b2 = *(const f4*)&BL[1536 + 4 * g];   // g==0 lanes: real head_b2
    f4 acc[4] = {b2, b2, b2, b2};
#pragma unroll
    for (int ks = 0; ks < 4; ++ks) {
      h8 A = *(const h8*)&WLB[r * 128 + ((ks * 32 + g * 8) ^ rsw)];
#pragma unroll
      for (int t = 0; t < 4; ++t)
        acc[t] = MFMA16(A, x[t][ks], acc[t], 0, 0, 0);
    }
    if (g == 0) {                      // lane r holds pixel r's rgba contiguously
#pragma unroll
      for (int t = 0; t < 4; ++t)
        *(f4*)&out[(bpix + pb + t * 16 + r) * 4] = acc[t];
    }
  }
}

// ---------------------------------------------------------------------------
extern "C" void kernel_launch(void* const* d_in, const int* in_sizes, int n_in,
                              void* d_out, int out_size, void* d_ws, size_t ws_size,
                              hipStream_t stream) {
  const int*   vert    = (const int*)  d_in[0];
  const float* bary    = (const float*)d_in[1];
  const float* view    = (const float*)d_in[2];
  const float* emb     = (const float*)d_in[3];
  const float* vde_W   = (const float*)d_in[4];
  const float* vde_b   = (const float*)d_in[5];
  const float* vh_W    = (const float*)d_in[6];
  const float* vh_b    = (const float*)d_in[7];
  const float* hid_W   = (const float*)d_in[8];
  const float* hid_b   = (const float*)d_in[9];
  const float* head_W0 = (const float*)d_in[10];
  const float* head_b0 = (const float*)d_in[11];
  const float* head_W1 = (const float*)d_in[12];
  const float* head_b1 = (const float*)d_in[13];
  const float* head_W2 = (const float*)d_in[14];
  const float* head_b2 = (const float*)d_in[15];
  u16* wsp = (u16*)d_ws;   // needs 403456 B

  rc_prep<<<788, 256, 0, stream>>>(vde_W, vh_W, hid_W, head_W0, head_W1, head_W2, wsp);
  rc_main<<<2048, 256, 0, stream>>>(vert, bary, view, emb, vde_b, vh_b, hid_b,
                                    head_b0, head_b1, head_b2, wsp, (float*)d_out);
}

// Round 9
// 380.805 us; speedup vs baseline: 1.4000x; 1.4000x over previous
//
#include <hip/hip_runtime.h>

typedef unsigned int  u32;
typedef unsigned long long u64;
typedef unsigned short u16;
typedef __attribute__((ext_vector_type(8))) _Float16 h8;   // MFMA A/B frag: 8 fp16 = 4 VGPR
typedef __attribute__((ext_vector_type(2))) _Float16 h2;   // packed fp16 pair
typedef __attribute__((ext_vector_type(4))) float    f4;   // MFMA C/D frag

#define RS    136    // X row stride (fp16): 272B rows, 16B-aligned, 2-way banks
#define PRS   40     // row stride for vde weights (K=18 padded to 32, stored 40)
#define PIXB  256    // pixels per block (8 waves x 32 pixels)
#define WOFF  5120   // vde region size (halves)
#define WT    16384  // one unpadded swizzled weight tile [128][128] (halves)
#define MFMA16 __builtin_amdgcn_mfma_f32_16x16x32_f16

__device__ __forceinline__ u16 f2h(float f) {
  _Float16 h = (_Float16)f;
  return __builtin_bit_cast(u16, h);
}
__device__ __forceinline__ u32 pkrtz(float a, float b) {
  return __builtin_bit_cast(u32, __builtin_amdgcn_cvt_pkrtz(a, b));
}
__device__ __forceinline__ u32 pkmul(u32 a, u32 b) {   // v_pk_mul_f16
  h2 r = __builtin_bit_cast(h2, a) * __builtin_bit_cast(h2, b);
  return __builtin_bit_cast(u32, r);
}
__device__ __forceinline__ u32 pkmax0(u32 a) {         // v_pk_max_f16 vs 0
  h2 z = {(_Float16)0.f, (_Float16)0.f};
  h2 r = __builtin_elementwise_max(__builtin_bit_cast(h2, a), z);
  return __builtin_bit_cast(u32, r);
}

// ---------------------------------------------------------------------------
// Prep: fp16 weights, transposed to [out][in].
// ws (halves): [0,5120) vdeT [128][40] (k<18 valid)
//   [5120 + j*16384), j=0..11: [128][128] tiles, XOR-SWIZZLED within rows:
//   element (n,k) stored at column k ^ ((n&7)<<3)  (involution; linear DMA +
//   swizzled ds_read_b128 -> near-conflict-free).
//   j: 0..2 vh, 3..8 hid, 9 headW0, 10 headW1, 11 headW2 (n>=4 zero)
// ---------------------------------------------------------------------------
__global__ __launch_bounds__(256) void rc_prep(
    const float* __restrict__ vde_W, const float* __restrict__ vh_W,
    const float* __restrict__ hid_W, const float* __restrict__ head_W0,
    const float* __restrict__ head_W1, const float* __restrict__ head_W2,
    u16* __restrict__ ws)
{
  const int TOT = WOFF + 12 * WT;   // 201728
  int i = blockIdx.x * 256 + threadIdx.x;
  if (i >= TOT) return;
  float val = 0.f;
  if (i < WOFF) {
    int n = i / PRS, k = i - n * PRS;
    if (k < 18) val = vde_W[k * 128 + n];
  } else {
    int t = i - WOFF;
    int j = t >> 14;
    int rr = t & 16383;
    int n = rr >> 7, kq = rr & 127;
    int k = kq ^ ((n & 7) << 3);          // element stored at this position
    if (j < 3)        val = vh_W[j * 16384 + k * 128 + n];
    else if (j < 9)   val = hid_W[(j - 3) * 16384 + k * 128 + n];
    else if (j == 9)  val = head_W0[k * 128 + n];
    else if (j == 10) val = head_W1[k * 128 + n];
    else              val = (n < 4) ? head_W2[k * 4 + n] : 0.f;
  }
  ws[i] = f2h(val);
}

// ---------------------------------------------------------------------------
// STAGE: DMA one 32KB weight tile global->LDS (linear; source pre-swizzled).
// 8 waves x 4 x global_load_lds(16B): wave w stages bytes [w*4096, w*4096+4096).
// ---------------------------------------------------------------------------
#define STAGE(WBUF, j) do {                                                   \
  const u16* _s = ws + WOFF + (j) * WT + w * 2048 + lane * 8;                 \
  _Pragma("unroll")                                                           \
  for (int _it = 0; _it < 4; ++_it)                                           \
    __builtin_amdgcn_global_load_lds(                                         \
        (const __attribute__((address_space(1))) void*)(_s + _it * 512),      \
        (__attribute__((address_space(3))) void*)&WBUF[w * 2048 + _it * 512], \
        16, 0, 0);                                                            \
} while (0)

// compute output-tile NT (2 pixel-tiles) with weights from LDS buffer WBUF.
// A-frag read applies the XOR swizzle; bias from BL (f32-exact C-init);
// epilogue: cvt_pkrtz -> packed relu -> [capture | pk_mul] -> ds_write_b64.
#define COMPUTE_NT(WBUF, NT) do {                                             \
  h8 Aw[4];                                                                   \
  _Pragma("unroll")                                                           \
  for (int ks = 0; ks < 4; ++ks)                                              \
    Aw[ks] = *(const h8*)&WBUF[((NT) * 16 + r) * 128 + ((ks * 32 + g * 8) ^ rsw)]; \
  f4 bini = *(const f4*)&BL[blb + (NT) * 16 + 4 * g];                         \
  f4 ac[2] = {bini, bini};                                                    \
  _Pragma("unroll")                                                           \
  for (int ks = 0; ks < 4; ++ks) {                                            \
    ac[0] = MFMA16(Aw[ks], x[0][ks], ac[0], 0, 0, 0);                         \
    ac[1] = MFMA16(Aw[ks], x[1][ks], ac[1], 0, 0, 0);                         \
  }                                                                           \
  const int col = (NT) * 16 + 4 * g;                                          \
  _Pragma("unroll")                                                           \
  for (int t = 0; t < 2; ++t) {                                               \
    u32 lo = pkmax0(pkrtz(ac[t][0], ac[t][1]));                               \
    u32 hi = pkmax0(pkrtz(ac[t][2], ac[t][3]));                               \
    if (mode == 1) {                       /* capture vh (packed) */          \
      vhp[t][NT][0] = lo; vhp[t][NT][1] = hi;                                 \
    } else {                                                                  \
      if (mode == 2) {                     /* h = relu(out) * vh */           \
        lo = pkmul(lo, vhp[t][NT][0]);                                        \
        hi = pkmul(hi, vhp[t][NT][1]);                                        \
      }                                                                       \
      *(uint2*)&X[xr[t] + col] = make_uint2(lo, hi);                          \
    }                                                                         \
  }                                                                           \
} while (0)

// one full 128x128 layer: issue next tile's DMA, compute from current LDS
// tile, optional gather, then __syncthreads (drains DMA = staging fence).
#define LAYER(LI, CURB, NXTB) do {                                            \
  const int li   = (LI);                                                      \
  const int blb  = (li + 1) * 128;                                            \
  const int mode = (li == 2) ? 1 : (li == 5) ? 2 : 0;                         \
  STAGE(NXTB, li + 1);                                                        \
  h8 x[2][4];                                                                 \
  _Pragma("unroll")                                                           \
  for (int t = 0; t < 2; ++t)                                                 \
    _Pragma("unroll")                                                         \
    for (int ks = 0; ks < 4; ++ks)                                            \
      x[t][ks] = *(const h8*)&X[xr[t] + ks * 32 + g * 8];                     \
  COMPUTE_NT(CURB, 0); COMPUTE_NT(CURB, 1);                                   \
  COMPUTE_NT(CURB, 2); COMPUTE_NT(CURB, 3);                                   \
  COMPUTE_NT(CURB, 4); COMPUTE_NT(CURB, 5);                                   \
  COMPUTE_NT(CURB, 6); COMPUTE_NT(CURB, 7);                                   \
  if (li == 2) do_gather();                                                   \
  __syncthreads();                                                            \
} while (0)

// ---------------------------------------------------------------------------
// Main fused kernel — LDS-staged weights, DMA double-buffer, 512-thread
// blocks: 8 waves x 32 px = 256 px/block, 141.8 KB LDS, 1 block/CU but
// 2 waves/SIMD (vs R8's 1) so ds_read/MFMA latency is co-scheduled away.
// ---------------------------------------------------------------------------
__global__ __launch_bounds__(512, 1) void rc_main(
    const int*   __restrict__ vert,  const float* __restrict__ bary,
    const float* __restrict__ view,  const float* __restrict__ emb,
    const float* __restrict__ vde_b, const float* __restrict__ vh_b,
    const float* __restrict__ hid_b, const float* __restrict__ head_b0,
    const float* __restrict__ head_b1, const float* __restrict__ head_b2,
    const u16*   __restrict__ ws,    float* __restrict__ out)
{
  __shared__ __align__(16) u16   X[PIXB * RS];   // 69632 B activations
  __shared__ __align__(16) u16   WLA[WT];        // 32768 B weight tile (even)
  __shared__ __align__(16) u16   WLB[WT];        // 32768 B weight tile (odd)
  __shared__ __align__(16) float BL[1664];       // 6656 B: all biases

  const int tid  = threadIdx.x;
  const int lane = tid & 63;
  const int w    = tid >> 6;        // wave 0..7
  const int r    = lane & 15;       // pixel-within-tile; A row
  const int g    = lane >> 4;       // k-group; D row group
  const int pb   = w * 32;          // wave's first pixel row (32 px/wave)
  const int rsw  = (r & 7) << 3;    // weight-read XOR swizzle (fp16 units)
  const size_t bpix = (size_t)blockIdx.x * PIXB;

  // ---- cooperative bias load into LDS
  for (int i = tid; i < 1664; i += 512) {
    float v;
    if      (i < 128)  v = vde_b[i];
    else if (i < 512)  v = vh_b[i - 128];
    else if (i < 1280) v = hid_b[i - 512];
    else if (i < 1408) v = head_b0[i - 1280];
    else if (i < 1536) v = head_b1[i - 1408];
    else if (i < 1540) v = head_b2[i - 1536];
    else               v = 0.f;
    BL[i] = v;
  }

  // ---- PE: lanes 0..31 compute their pixel's sin/cos encoding into X[row][0..32)
  if (lane < 32) {
    const int p = pb + lane;
    const float* vd = view + (bpix + p) * 3;
    const float SG0 = 6.28318530718f;   // 2pi / 0.9^0
    const float SG1 = 6.50777324f;      // 2pi / 0.9^(1/3)
    const float SG2 = 6.74038866f;      // 2pi / 0.9^(2/3)
    u32 pw[16];
#pragma unroll
    for (int i = 0; i < 3; ++i) {
      float x = vd[i];
      float s0 = __sinf(x * SG0), c0 = __cosf(x * SG0);
      float s1 = __sinf(x * SG1), c1 = __cosf(x * SG1);
      float s2 = __sinf(x * SG2), c2 = __cosf(x * SG2);
      pw[i * 3 + 0] = (u32)f2h(s0) | ((u32)f2h(s1) << 16);
      pw[i * 3 + 1] = (u32)f2h(s2) | ((u32)f2h(c0) << 16);
      pw[i * 3 + 2] = (u32)f2h(c1) | ((u32)f2h(c2) << 16);
    }
#pragma unroll
    for (int q = 9; q < 16; ++q) pw[q] = 0u;   // zero-pad k = 18..31
    uint4* dst = (uint4*)&X[p * RS];
#pragma unroll
    for (int q = 0; q < 4; ++q)
      dst[q] = make_uint4(pw[4*q], pw[4*q+1], pw[4*q+2], pw[4*q+3]);
  }
  __syncthreads();

  const int xr[2] = { (pb + r) * RS, (pb + 16 + r) * RS };

  // ---- gather closure (used at li==2): embedding + renorm + bary -> X
  auto do_gather = [&]() {
#pragma unroll 4
    for (int i = 0; i < 8; ++i) {
      int p = pb + g * 8 + i;                // 16-lane group g handles 8 pixels
      size_t gp = bpix + p;
      const int*   vi = vert + gp * 3;
      const float* by = bary + gp * 3;
      f4 va = {0.f,0.f,0.f,0.f}, vb = {0.f,0.f,0.f,0.f};
#pragma unroll
      for (int vt = 0; vt < 3; ++vt) {
        int id = vi[vt] + 1;
        const float* row = emb + (size_t)id * 128 + r * 8;  // lane r: 8 chans
        f4 e0 = *(const f4*)row;
        f4 e1 = *(const f4*)(row + 4);
        float ss = e0[0]*e0[0] + e0[1]*e0[1] + e0[2]*e0[2] + e0[3]*e0[3]
                 + e1[0]*e1[0] + e1[1]*e1[1] + e1[2]*e1[2] + e1[3]*e1[3];
        ss += __shfl_xor(ss, 1);             // reduce within the 16-lane group
        ss += __shfl_xor(ss, 2);
        ss += __shfl_xor(ss, 4);
        ss += __shfl_xor(ss, 8);
        float nrm = sqrtf(ss);
        float sc  = (nrm > 1.f) ? (1.f / (nrm + 1e-7f)) : 1.f;  // torch max_norm
        float wt  = by[vt] * sc;
#pragma unroll
        for (int j = 0; j < 4; ++j) { va[j] += wt * e0[j]; vb[j] += wt * e1[j]; }
      }
      h8 o;
#pragma unroll
      for (int j = 0; j < 4; ++j) { o[j] = (_Float16)va[j]; o[j+4] = (_Float16)vb[j]; }
      *(h8*)&X[p * RS + r * 8] = o;
    }
  };

  // ---- L0: vde (K=18 padded to 32) from global; stage layer-0 tile meanwhile
  STAGE(WLA, 0);
  {
    h8 Av[8];
#pragma unroll
    for (int nt = 0; nt < 8; ++nt)
      Av[nt] = *(const h8*)&ws[(nt * 16 + r) * PRS + g * 8];
    h8 pe[2];
#pragma unroll
    for (int t = 0; t < 2; ++t) pe[t] = *(const h8*)&X[xr[t] + g * 8];
#pragma unroll
    for (int nt = 0; nt < 8; ++nt) {
      f4 bini = *(const f4*)&BL[nt * 16 + 4 * g];
      const int col = nt * 16 + 4 * g;
#pragma unroll
      for (int t = 0; t < 2; ++t) {
        f4 acc = MFMA16(Av[nt], pe[t], bini, 0, 0, 0);
        *(uint2*)&X[xr[t] + col] =          // no relu on vde output
          make_uint2(pkrtz(acc[0], acc[1]), pkrtz(acc[2], acc[3]));
      }
    }
  }
  __syncthreads();   // WLA tile landed (DMA had the whole vde phase)

  // ---- 11 full 128x128 layers: even layers read WLA/stage WLB, odd converse
  u32 vhp[2][8][2];   // captured vh: set at li==2, used at li==5
#pragma unroll 1
  for (int lp = 0; lp < 5; ++lp) {
    LAYER(2 * lp,     WLA, WLB);
    LAYER(2 * lp + 1, WLB, WLA);
  }
  LAYER(10, WLA, WLB);   // stages j=11 (head tile) into WLB

  // ---- head_W2 (128 -> 4) + head_b2 from WLB
  {
    h8 x[2][4];
#pragma unroll
    for (int t = 0; t < 2; ++t)
#pragma unroll
      for (int ks = 0; ks < 4; ++ks)
        x[t][ks] = *(const h8*)&X[xr[t] + ks * 32 + g * 8];
    f4 b2 = *(const f4*)&BL[1536 + 4 * g];   // g==0 lanes: real head_b2
    f4 acc[2] = {b2, b2};
#pragma unroll
    for (int ks = 0; ks < 4; ++ks) {
      h8 A = *(const h8*)&WLB[r * 128 + ((ks * 32 + g * 8) ^ rsw)];
#pragma unroll
      for (int t = 0; t < 2; ++t)
        acc[t] = MFMA16(A, x[t][ks], acc[t], 0, 0, 0);
    }
    if (g == 0) {                      // lane r holds pixel r's rgba contiguously
#pragma unroll
      for (int t = 0; t < 2; ++t)
        *(f4*)&out[(bpix + pb + t * 16 + r) * 4] = acc[t];
    }
  }
}

// ---------------------------------------------------------------------------
extern "C" void kernel_launch(void* const* d_in, const int* in_sizes, int n_in,
                              void* d_out, int out_size, void* d_ws, size_t ws_size,
                              hipStream_t stream) {
  const int*   vert    = (const int*)  d_in[0];
  const float* bary    = (const float*)d_in[1];
  const float* view    = (const float*)d_in[2];
  const float* emb     = (const float*)d_in[3];
  const float* vde_W   = (const float*)d_in[4];
  const float* vde_b   = (const float*)d_in[5];
  const float* vh_W    = (const float*)d_in[6];
  const float* vh_b    = (const float*)d_in[7];
  const float* hid_W   = (const float*)d_in[8];
  const float* hid_b   = (const float*)d_in[9];
  const float* head_W0 = (const float*)d_in[10];
  const float* head_b0 = (const float*)d_in[11];
  const float* head_W1 = (const float*)d_in[12];
  const float* head_b1 = (const float*)d_in[13];
  const float* head_W2 = (const float*)d_in[14];
  const float* head_b2 = (const float*)d_in[15];
  u16* wsp = (u16*)d_ws;   // needs 403456 B

  rc_prep<<<788, 256, 0, stream>>>(vde_W, vh_W, hid_W, head_W0, head_W1, head_W2, wsp);
  rc_main<<<2048, 512, 0, stream>>>(vert, bary, view, emb, vde_b, vh_b, hid_b,
                                    head_b0, head_b1, head_b2, wsp, (float*)d_out);
}

// Round 10
// 373.377 us; speedup vs baseline: 1.4278x; 1.0199x over previous
//
#include <hip/hip_runtime.h>

typedef unsigned int  u32;
typedef unsigned long long u64;
typedef unsigned short u16;
typedef __attribute__((ext_vector_type(8))) _Float16 h8;   // MFMA A/B frag: 8 fp16 = 4 VGPR
typedef __attribute__((ext_vector_type(2))) _Float16 h2;   // packed fp16 pair
typedef __attribute__((ext_vector_type(4))) float    f4;   // MFMA C/D frag

#define RS    136    // X row stride (fp16): 272B rows, 16B-aligned
#define PRS   40     // row stride for vde weights (K=18 padded to 32, stored 40)
#define PIXB  256    // pixels per block (4 pixel-groups x 64 px)
#define WOFF  5120   // vde region size (halves)
#define WT    16384  // one unpadded swizzled weight tile [128][128] (halves)
#define MFMA16 __builtin_amdgcn_mfma_f32_16x16x32_f16

__device__ __forceinline__ u16 f2h(float f) {
  _Float16 h = (_Float16)f;
  return __builtin_bit_cast(u16, h);
}
__device__ __forceinline__ u32 pkrtz(float a, float b) {
  return __builtin_bit_cast(u32, __builtin_amdgcn_cvt_pkrtz(a, b));
}
__device__ __forceinline__ u32 pkmul(u32 a, u32 b) {   // v_pk_mul_f16
  h2 r = __builtin_bit_cast(h2, a) * __builtin_bit_cast(h2, b);
  return __builtin_bit_cast(u32, r);
}
__device__ __forceinline__ u32 pkmax0(u32 a) {         // v_pk_max_f16 vs 0
  h2 z = {(_Float16)0.f, (_Float16)0.f};
  h2 r = __builtin_elementwise_max(__builtin_bit_cast(h2, a), z);
  return __builtin_bit_cast(u32, r);
}

// ---------------------------------------------------------------------------
// Prep: fp16 weights, transposed to [out][in].
// ws (halves): [0,5120) vdeT [128][40] (k<18 valid)
//   [5120 + j*16384), j=0..11: [128][128] tiles, XOR-SWIZZLED within rows:
//   element (n,k) stored at column k ^ ((n&7)<<3).
//   j: 0..2 vh, 3..8 hid, 9 headW0, 10 headW1, 11 headW2 (n>=4 zero)
// ---------------------------------------------------------------------------
__global__ __launch_bounds__(256) void rc_prep(
    const float* __restrict__ vde_W, const float* __restrict__ vh_W,
    const float* __restrict__ hid_W, const float* __restrict__ head_W0,
    const float* __restrict__ head_W1, const float* __restrict__ head_W2,
    u16* __restrict__ ws)
{
  const int TOT = WOFF + 12 * WT;   // 201728
  int i = blockIdx.x * 256 + threadIdx.x;
  if (i >= TOT) return;
  float val = 0.f;
  if (i < WOFF) {
    int n = i / PRS, k = i - n * PRS;
    if (k < 18) val = vde_W[k * 128 + n];
  } else {
    int t = i - WOFF;
    int j = t >> 14;
    int rr = t & 16383;
    int n = rr >> 7, kq = rr & 127;
    int k = kq ^ ((n & 7) << 3);          // element stored at this position
    if (j < 3)        val = vh_W[j * 16384 + k * 128 + n];
    else if (j < 9)   val = hid_W[(j - 3) * 16384 + k * 128 + n];
    else if (j == 9)  val = head_W0[k * 128 + n];
    else if (j == 10) val = head_W1[k * 128 + n];
    else              val = (n < 4) ? head_W2[k * 4 + n] : 0.f;
  }
  ws[i] = f2h(val);
}

// ---------------------------------------------------------------------------
// STAGE: DMA one 32KB weight tile global->LDS (linear; source pre-swizzled).
// 8 waves x 4 x global_load_lds(16B).
// ---------------------------------------------------------------------------
#define STAGE(WBUF, j) do {                                                   \
  const u16* _s = ws + WOFF + (j) * WT + w * 2048 + lane * 8;                 \
  _Pragma("unroll")                                                           \
  for (int _it = 0; _it < 4; ++_it)                                           \
    __builtin_amdgcn_global_load_lds(                                         \
        (const __attribute__((address_space(1))) void*)(_s + _it * 512),      \
        (__attribute__((address_space(3))) void*)&WBUF[w * 2048 + _it * 512], \
        16, 0, 0);                                                            \
} while (0)

// load the 4 ks A-frags of local channel tile NTL from LDS buffer WBUF
#define LOADA(AA, NTL, WBUF) do {                                             \
  _Pragma("unroll")                                                           \
  for (int ks = 0; ks < 4; ++ks)                                              \
    AA[ks] = *(const h8*)&WBUF[(nbase + (NTL) * 16 + r) * 128 +               \
                               ((ks * 32 + g * 8) ^ rsw)];                    \
} while (0)

// compute local channel tile NTL (4 pixel-tiles) from A-regs AA.
// epilogue: cvt_pkrtz -> packed relu -> [capture | pk_mul] -> ds_write_b64.
#define COMPUTE_NT(NTL, AA) do {                                              \
  f4 bini = *(const f4*)&BL[blb + nbase + (NTL) * 16 + 4 * g];                \
  f4 ac[4] = {bini, bini, bini, bini};                                        \
  _Pragma("unroll")                                                           \
  for (int ks = 0; ks < 4; ++ks) {                                            \
    ac[0] = MFMA16(AA[ks], x[0][ks], ac[0], 0, 0, 0);                         \
    ac[1] = MFMA16(AA[ks], x[1][ks], ac[1], 0, 0, 0);                         \
    ac[2] = MFMA16(AA[ks], x[2][ks], ac[2], 0, 0, 0);                         \
    ac[3] = MFMA16(AA[ks], x[3][ks], ac[3], 0, 0, 0);                         \
  }                                                                           \
  const int col = nbase + (NTL) * 16 + 4 * g;                                 \
  _Pragma("unroll")                                                           \
  for (int t = 0; t < 4; ++t) {                                               \
    u32 lo = pkmax0(pkrtz(ac[t][0], ac[t][1]));                               \
    u32 hi = pkmax0(pkrtz(ac[t][2], ac[t][3]));                               \
    if (mode == 1) {                       /* capture vh (packed) */          \
      vhp[t][NTL][0] = lo; vhp[t][NTL][1] = hi;                               \
    } else {                                                                  \
      if (mode == 2) {                     /* h = relu(out) * vh */           \
        lo = pkmul(lo, vhp[t][NTL][0]);                                       \
        hi = pkmul(hi, vhp[t][NTL][1]);                                       \
      }                                                                       \
      *(uint2*)&X[xr[t] + col] = make_uint2(lo, hi);                          \
    }                                                                         \
  }                                                                           \
} while (0)

// one full 128x128 layer at 64px x 64ch per wave, A double-buffered in regs.
#define LAYER(LI, CURB, NXTB) do {                                            \
  const int li   = (LI);                                                      \
  const int blb  = (li + 1) * 128;                                            \
  const int mode = (li == 2) ? 1 : (li == 5) ? 2 : 0;                         \
  STAGE(NXTB, li + 1);                                                        \
  h8 x[4][4];                                                                 \
  _Pragma("unroll")                                                           \
  for (int t = 0; t < 4; ++t)                                                 \
    _Pragma("unroll")                                                         \
    for (int ks = 0; ks < 4; ++ks)                                            \
      x[t][ks] = *(const h8*)&X[xr[t] + ks * 32 + g * 8];                     \
  h8 Aa[4], Ab[4];                                                            \
  LOADA(Aa, 0, CURB); LOADA(Ab, 1, CURB);                                     \
  COMPUTE_NT(0, Aa);  LOADA(Aa, 2, CURB);                                     \
  COMPUTE_NT(1, Ab);  LOADA(Ab, 3, CURB);                                     \
  COMPUTE_NT(2, Aa);                                                          \
  COMPUTE_NT(3, Ab);                                                          \
  if (li == 2) do_gather();                                                   \
  __syncthreads();                                                            \
} while (0)

// ---------------------------------------------------------------------------
// Main fused kernel — LDS-staged weights (DMA double-buffer), 512 threads,
// 2-D wave tiling: 8 waves = 4 pixel-groups (64 px) x 2 channel-halves
// (64 ch). Halves the dominant A-frag LDS reads vs R9; each A-frag feeds
// 16 MFMA so the next tile's ds_reads hide under compute.
// ---------------------------------------------------------------------------
__global__ __launch_bounds__(512, 1) void rc_main(
    const int*   __restrict__ vert,  const float* __restrict__ bary,
    const float* __restrict__ view,  const float* __restrict__ emb,
    const float* __restrict__ vde_b, const float* __restrict__ vh_b,
    const float* __restrict__ hid_b, const float* __restrict__ head_b0,
    const float* __restrict__ head_b1, const float* __restrict__ head_b2,
    const u16*   __restrict__ ws,    float* __restrict__ out)
{
  __shared__ __align__(16) u16   X[PIXB * RS];   // 69632 B activations
  __shared__ __align__(16) u16   WLA[WT];        // 32768 B weight tile (even)
  __shared__ __align__(16) u16   WLB[WT];        // 32768 B weight tile (odd)
  __shared__ __align__(16) float BL[1664];       // 6656 B: all biases

  const int tid  = threadIdx.x;
  const int lane = tid & 63;
  const int w    = tid >> 6;        // wave 0..7
  const int wq   = w >> 1;          // pixel group 0..3
  const int wc   = w & 1;           // channel half 0..1
  const int r    = lane & 15;       // pixel-within-tile; A row
  const int g    = lane >> 4;       // k-group; D row group
  const int pbase = wq * 64;        // wave's first pixel row (64 px/wave)
  const int nbase = wc * 64;        // wave's first output channel
  const int rsw  = (r & 7) << 3;    // weight-read XOR swizzle (fp16 units)
  const size_t bpix = (size_t)blockIdx.x * PIXB;

  // ---- cooperative bias load into LDS
  for (int i = tid; i < 1664; i += 512) {
    float v;
    if      (i < 128)  v = vde_b[i];
    else if (i < 512)  v = vh_b[i - 128];
    else if (i < 1280) v = hid_b[i - 512];
    else if (i < 1408) v = head_b0[i - 1280];
    else if (i < 1536) v = head_b1[i - 1408];
    else if (i < 1540) v = head_b2[i - 1536];
    else               v = 0.f;
    BL[i] = v;
  }

  // ---- PE: lanes 0..31 of each wave compute one pixel's encoding (256 px)
  if (lane < 32) {
    const int p = w * 32 + lane;
    const float* vd = view + (bpix + p) * 3;
    const float SG0 = 6.28318530718f;   // 2pi / 0.9^0
    const float SG1 = 6.50777324f;      // 2pi / 0.9^(1/3)
    const float SG2 = 6.74038866f;      // 2pi / 0.9^(2/3)
    u32 pw[16];
#pragma unroll
    for (int i = 0; i < 3; ++i) {
      float x = vd[i];
      float s0 = __sinf(x * SG0), c0 = __cosf(x * SG0);
      float s1 = __sinf(x * SG1), c1 = __cosf(x * SG1);
      float s2 = __sinf(x * SG2), c2 = __cosf(x * SG2);
      pw[i * 3 + 0] = (u32)f2h(s0) | ((u32)f2h(s1) << 16);
      pw[i * 3 + 1] = (u32)f2h(s2) | ((u32)f2h(c0) << 16);
      pw[i * 3 + 2] = (u32)f2h(c1) | ((u32)f2h(c2) << 16);
    }
#pragma unroll
    for (int q = 9; q < 16; ++q) pw[q] = 0u;   // zero-pad k = 18..31
    uint4* dst = (uint4*)&X[p * RS];
#pragma unroll
    for (int q = 0; q < 4; ++q)
      dst[q] = make_uint4(pw[4*q], pw[4*q+1], pw[4*q+2], pw[4*q+3]);
  }
  __syncthreads();

  const int xr[4] = { (pbase +      r) * RS, (pbase + 16 + r) * RS,
                      (pbase + 32 + r) * RS, (pbase + 48 + r) * RS };

  // ---- gather closure (used at li==2): embedding + renorm + bary -> X
  // wave w handles pixels [w*32, w*32+32) — independent of the 2-D tiling;
  // the layer barrier after it republishes X for all readers.
  auto do_gather = [&]() {
#pragma unroll 4
    for (int i = 0; i < 8; ++i) {
      int p = w * 32 + g * 8 + i;            // 16-lane group g handles 8 pixels
      size_t gp = bpix + p;
      const int*   vi = vert + gp * 3;
      const float* by = bary + gp * 3;
      f4 va = {0.f,0.f,0.f,0.f}, vb = {0.f,0.f,0.f,0.f};
#pragma unroll
      for (int vt = 0; vt < 3; ++vt) {
        int id = vi[vt] + 1;
        const float* row = emb + (size_t)id * 128 + r * 8;  // lane r: 8 chans
        f4 e0 = *(const f4*)row;
        f4 e1 = *(const f4*)(row + 4);
        float ss = e0[0]*e0[0] + e0[1]*e0[1] + e0[2]*e0[2] + e0[3]*e0[3]
                 + e1[0]*e1[0] + e1[1]*e1[1] + e1[2]*e1[2] + e1[3]*e1[3];
        ss += __shfl_xor(ss, 1);             // reduce within the 16-lane group
        ss += __shfl_xor(ss, 2);
        ss += __shfl_xor(ss, 4);
        ss += __shfl_xor(ss, 8);
        float nrm = sqrtf(ss);
        float sc  = (nrm > 1.f) ? (1.f / (nrm + 1e-7f)) : 1.f;  // torch max_norm
        float wt  = by[vt] * sc;
#pragma unroll
        for (int j = 0; j < 4; ++j) { va[j] += wt * e0[j]; vb[j] += wt * e1[j]; }
      }
      h8 o;
#pragma unroll
      for (int j = 0; j < 4; ++j) { o[j] = (_Float16)va[j]; o[j+4] = (_Float16)vb[j]; }
      *(h8*)&X[p * RS + r * 8] = o;
    }
  };

  // ---- L0: vde (K=18 padded to 32) from global; stage layer-0 tile meanwhile
  STAGE(WLA, 0);
  {
    h8 Av[4];
#pragma unroll
    for (int ntl = 0; ntl < 4; ++ntl)
      Av[ntl] = *(const h8*)&ws[(nbase + ntl * 16 + r) * PRS + g * 8];
    h8 pe[4];
#pragma unroll
    for (int t = 0; t < 4; ++t) pe[t] = *(const h8*)&X[xr[t] + g * 8];
#pragma unroll
    for (int ntl = 0; ntl < 4; ++ntl) {
      f4 bini = *(const f4*)&BL[nbase + ntl * 16 + 4 * g];
      const int col = nbase + ntl * 16 + 4 * g;
#pragma unroll
      for (int t = 0; t < 4; ++t) {
        f4 acc = MFMA16(Av[ntl], pe[t], bini, 0, 0, 0);
        *(uint2*)&X[xr[t] + col] =          // no relu on vde output
          make_uint2(pkrtz(acc[0], acc[1]), pkrtz(acc[2], acc[3]));
      }
    }
  }
  __syncthreads();   // WLA tile landed (DMA had the whole vde phase)

  // ---- 11 full 128x128 layers: even layers read WLA/stage WLB, odd converse
  u32 vhp[4][4][2];   // captured vh: set at li==2, used at li==5
#pragma unroll 1
  for (int lp = 0; lp < 5; ++lp) {
    LAYER(2 * lp,     WLA, WLB);
    LAYER(2 * lp + 1, WLB, WLA);
  }
  LAYER(10, WLA, WLB);   // stages j=11 (head tile) into WLB

  // ---- head_W2 (128 -> 4) + head_b2 from WLB (channel-half-0 waves only)
  if (wc == 0) {
    h8 x[4][4];
#pragma unroll
    for (int t = 0; t < 4; ++t)
#pragma unroll
      for (int ks = 0; ks < 4; ++ks)
        x[t][ks] = *(const h8*)&X[xr[t] + ks * 32 + g * 8];
    f4 b2 = *(const f4*)&BL[1536 + 4 * g];   // g==0 lanes: real head_b2
    f4 acc[4] = {b2, b2, b2, b2};
#pragma unroll
    for (int ks = 0; ks < 4; ++ks) {
      h8 A = *(const h8*)&WLB[r * 128 + ((ks * 32 + g * 8) ^ rsw)];
#pragma unroll
      for (int t = 0; t < 4; ++t)
        acc[t] = MFMA16(A, x[t][ks], acc[t], 0, 0, 0);
    }
    if (g == 0) {                      // lane r holds pixel r's rgba contiguously
#pragma unroll
      for (int t = 0; t < 4; ++t)
        *(f4*)&out[(bpix + pbase + t * 16 + r) * 4] = acc[t];
    }
  }
}

// ---------------------------------------------------------------------------
extern "C" void kernel_launch(void* const* d_in, const int* in_sizes, int n_in,
                              void* d_out, int out_size, void* d_ws, size_t ws_size,
                              hipStream_t stream) {
  const int*   vert    = (const int*)  d_in[0];
  const float* bary    = (const float*)d_in[1];
  const float* view    = (const float*)d_in[2];
  const float* emb     = (const float*)d_in[3];
  const float* vde_W   = (const float*)d_in[4];
  const float* vde_b   = (const float*)d_in[5];
  const float* vh_W    = (const float*)d_in[6];
  const float* vh_b    = (const float*)d_in[7];
  const float* hid_W   = (const float*)d_in[8];
  const float* hid_b   = (const float*)d_in[9];
  const float* head_W0 = (const float*)d_in[10];
  const float* head_b0 = (const float*)d_in[11];
  const float* head_W1 = (const float*)d_in[12];
  const float* head_b1 = (const float*)d_in[13];
  const float* head_W2 = (const float*)d_in[14];
  const float* head_b2 = (const float*)d_in[15];
  u16* wsp = (u16*)d_ws;   // needs 403456 B

  rc_prep<<<788, 256, 0, stream>>>(vde_W, vh_W, hid_W, head_W0, head_W1, head_W2, wsp);
  rc_main<<<2048, 512, 0, stream>>>(vert, bary, view, emb, vde_b, vh_b, hid_b,
                                    head_b0, head_b1, head_b2, wsp, (float*)d_out);
}

// Round 12
// 348.592 us; speedup vs baseline: 1.5294x; 1.0711x over previous
//
#include <hip/hip_runtime.h>

typedef unsigned int  u32;
typedef unsigned short u16;
typedef __attribute__((ext_vector_type(8))) _Float16 h8;   // MFMA A/B frag: 8 fp16 = 4 VGPR
typedef __attribute__((ext_vector_type(2))) _Float16 h2;   // packed fp16 pair
typedef __attribute__((ext_vector_type(4))) float    f4;   // MFMA C/D frag

#define RS    136    // X row stride (fp16): 272B rows, 16B-aligned
#define PRS   40     // row stride for vde weights (K=18 padded to 32, stored 40)
#define PIXB  128    // pixels per block (4 px-groups x 32 px)
#define WOFF  5120   // vde region size (halves)
#define WT    16384  // one unpadded swizzled weight tile [128][128] (halves)
#define MFMA16 __builtin_amdgcn_mfma_f32_16x16x32_f16

__device__ __forceinline__ u16 f2h(float f) {
  _Float16 h = (_Float16)f;
  return __builtin_bit_cast(u16, h);
}
__device__ __forceinline__ u32 pkrtz(float a, float b) {
  return __builtin_bit_cast(u32, __builtin_amdgcn_cvt_pkrtz(a, b));
}
__device__ __forceinline__ u32 pkmul(u32 a, u32 b) {   // v_pk_mul_f16
  h2 r = __builtin_bit_cast(h2, a) * __builtin_bit_cast(h2, b);
  return __builtin_bit_cast(u32, r);
}
__device__ __forceinline__ u32 pkmax0(u32 a) {         // v_pk_max_f16 vs 0
  h2 z = {(_Float16)0.f, (_Float16)0.f};
  h2 r = __builtin_elementwise_max(__builtin_bit_cast(h2, a), z);
  return __builtin_bit_cast(u32, r);
}

// ---------------------------------------------------------------------------
// Prep: fp16 weights, transposed to [out][in].
// ws (halves): [0,5120) vdeT [128][40] (k<18 valid)
//   [5120 + j*16384), j=0..11: [128][128] tiles, XOR-SWIZZLED within rows:
//   element (n,k) stored at column k ^ ((n&7)<<3).
//   j: 0..2 vh, 3..8 hid, 9 headW0, 10 headW1, 11 headW2 (n>=4 zero)
// ---------------------------------------------------------------------------
__global__ __launch_bounds__(256) void rc_prep(
    const float* __restrict__ vde_W, const float* __restrict__ vh_W,
    const float* __restrict__ hid_W, const float* __restrict__ head_W0,
    const float* __restrict__ head_W1, const float* __restrict__ head_W2,
    u16* __restrict__ ws)
{
  const int TOT = WOFF + 12 * WT;   // 201728
  int i = blockIdx.x * 256 + threadIdx.x;
  if (i >= TOT) return;
  float val = 0.f;
  if (i < WOFF) {
    int n = i / PRS, k = i - n * PRS;
    if (k < 18) val = vde_W[k * 128 + n];
  } else {
    int t = i - WOFF;
    int j = t >> 14;
    int rr = t & 16383;
    int n = rr >> 7, kq = rr & 127;
    int k = kq ^ ((n & 7) << 3);          // element stored at this position
    if (j < 3)        val = vh_W[j * 16384 + k * 128 + n];
    else if (j < 9)   val = hid_W[(j - 3) * 16384 + k * 128 + n];
    else if (j == 9)  val = head_W0[k * 128 + n];
    else if (j == 10) val = head_W1[k * 128 + n];
    else              val = (n < 4) ? head_W2[k * 4 + n] : 0.f;
  }
  ws[i] = f2h(val);
}

// ---------------------------------------------------------------------------
// STAGE: DMA one 32KB weight tile global->LDS (linear; source pre-swizzled).
// 8 waves x 4 x global_load_lds(16B). LDS dest is the WAVE-UNIFORM base;
// HW adds lane*16B (m104 semantics — matches the per-lane source below).
// ---------------------------------------------------------------------------
#define STAGE(j) do {                                                         \
  const u16* _s = ws + WOFF + (j) * WT + w * 512 + lane * 8;                  \
  _Pragma("unroll")                                                           \
  for (int _it = 0; _it < 4; ++_it)                                           \
    __builtin_amdgcn_global_load_lds(                                         \
        (const __attribute__((address_space(1))) void*)(_s + _it * 4096),     \
        (__attribute__((address_space(3))) void*)&WL[w * 512 + _it * 4096],   \
        16, 0, 0);                                                            \
} while (0)

// load the 4 ks A-frags of local channel tile NTL from WL (swizzled read)
#define LOADA(AA, NTL) do {                                                   \
  _Pragma("unroll")                                                           \
  for (int ks = 0; ks < 4; ++ks)                                              \
    AA[ks] = *(const h8*)&WL[(nbase + (NTL) * 16 + r) * 128 +                 \
                             ((ks * 32 + g * 8) ^ rsw)];                      \
} while (0)

// compute local channel tile NTL (2 pixel-tiles) from A-regs AA.
// epilogue: cvt_pkrtz -> packed relu -> [capture | pk_mul] -> ds_write_b64.
#define COMPUTE_NT(NTL, AA) do {                                              \
  f4 bini = *(const f4*)&BL[blb + nbase + (NTL) * 16 + 4 * g];                \
  f4 ac[2] = {bini, bini};                                                    \
  _Pragma("unroll")                                                           \
  for (int ks = 0; ks < 4; ++ks) {                                            \
    ac[0] = MFMA16(AA[ks], x[0][ks], ac[0], 0, 0, 0);                         \
    ac[1] = MFMA16(AA[ks], x[1][ks], ac[1], 0, 0, 0);                         \
  }                                                                           \
  const int col = nbase + (NTL) * 16 + 4 * g;                                 \
  _Pragma("unroll")                                                           \
  for (int t = 0; t < 2; ++t) {                                               \
    u32 lo = pkmax0(pkrtz(ac[t][0], ac[t][1]));                               \
    u32 hi = pkmax0(pkrtz(ac[t][2], ac[t][3]));                               \
    if (mode == 1) {                       /* capture vh (packed) */          \
      vhp[t][NTL][0] = lo; vhp[t][NTL][1] = hi;                               \
    } else {                                                                  \
      if (mode == 2) {                     /* h = relu(out) * vh */           \
        lo = pkmul(lo, vhp[t][NTL][0]);                                       \
        hi = pkmul(hi, vhp[t][NTL][1]);                                       \
      }                                                                       \
      *(uint2*)&X[xr[t] + col] = make_uint2(lo, hi);                          \
    }                                                                         \
  }                                                                           \
} while (0)

// one full 128x128 layer at 32px x 64ch per wave.
// RACE NOTE: waves (pg,0) and (pg,1) share pixel rows — each reads all 128
// cols then writes its 64-col half. The barrier between the reads and the
// first COMPUTE_NT write is REQUIRED (R11 failed without it: with 2
// blocks/CU the partner wave can lag past the write point).
#define LAYER(LI) do {                                                        \
  const int li   = (LI);                                                      \
  const int blb  = (li + 1) * 128;                                            \
  const int mode = (li == 2) ? 1 : (li == 5) ? 2 : 0;                         \
  h8 x[2][4];                                                                 \
  _Pragma("unroll")                                                           \
  for (int t = 0; t < 2; ++t)                                                 \
    _Pragma("unroll")                                                         \
    for (int ks = 0; ks < 4; ++ks)                                            \
      x[t][ks] = *(const h8*)&X[xr[t] + ks * 32 + g * 8];                     \
  h8 Aa[4], Ab[4];                                                            \
  LOADA(Aa, 0); LOADA(Ab, 1);                                                 \
  __syncthreads();                 /* all X reads done before any X write */  \
  COMPUTE_NT(0, Aa);  LOADA(Aa, 2);                                           \
  COMPUTE_NT(1, Ab);  LOADA(Ab, 3);                                           \
  COMPUTE_NT(2, Aa);                                                          \
  COMPUTE_NT(3, Ab);                                                          \
  if (li == 2) { __syncthreads(); do_gather(); }                              \
  __syncthreads();                 /* WL reads + X writes complete */         \
  STAGE(li + 1);                                                              \
  __syncthreads();                 /* DMA drained; WL = next layer tile */    \
} while (0)

// ---------------------------------------------------------------------------
// Main fused kernel — LDS-staged weights (single buffer), 512 threads,
// 128 px/block, 8 waves = 4 px-groups (32 px) x 2 ch-halves (64 ch).
// 74.2 KB LDS -> 2 blocks/CU = 4 waves/SIMD: twin blocks stagger, so one
// block's MFMA covers the other's staging drain and ds_read latency.
// ---------------------------------------------------------------------------
__global__ __launch_bounds__(512, 4) void rc_main(
    const int*   __restrict__ vert,  const float* __restrict__ bary,
    const float* __restrict__ view,  const float* __restrict__ emb,
    const float* __restrict__ vde_b, const float* __restrict__ vh_b,
    const float* __restrict__ hid_b, const float* __restrict__ head_b0,
    const float* __restrict__ head_b1, const float* __restrict__ head_b2,
    const u16*   __restrict__ ws,    float* __restrict__ out)
{
  __shared__ __align__(16) u16   X[PIXB * RS];   // 34816 B activations
  __shared__ __align__(16) u16   WL[WT];         // 32768 B weight tile
  __shared__ __align__(16) float BL[1664];       // 6656 B: all biases

  const int tid  = threadIdx.x;
  const int lane = tid & 63;
  const int w    = tid >> 6;        // wave 0..7
  const int pg   = w >> 1;          // pixel group 0..3
  const int cg   = w & 1;           // channel half 0..1
  const int r    = lane & 15;       // pixel-within-tile; A row
  const int g    = lane >> 4;       // k-group; D row group
  const int pbase = pg * 32;        // wave's first pixel row (32 px/wave)
  const int nbase = cg * 64;        // wave's first output channel
  const int rsw  = (r & 7) << 3;    // weight-read XOR swizzle (fp16 units)
  const size_t bpix = (size_t)blockIdx.x * PIXB;

  // ---- cooperative bias load into LDS
  for (int i = tid; i < 1664; i += 512) {
    float v;
    if      (i < 128)  v = vde_b[i];
    else if (i < 512)  v = vh_b[i - 128];
    else if (i < 1280) v = hid_b[i - 512];
    else if (i < 1408) v = head_b0[i - 1280];
    else if (i < 1536) v = head_b1[i - 1408];
    else if (i < 1540) v = head_b2[i - 1536];
    else               v = 0.f;
    BL[i] = v;
  }

  // ---- PE: threads 0..127 compute one pixel's encoding into X[row][0..32)
  if (tid < PIXB) {
    const int p = tid;
    const float* vd = view + (bpix + p) * 3;
    const float SG0 = 6.28318530718f;   // 2pi / 0.9^0
    const float SG1 = 6.50777324f;      // 2pi / 0.9^(1/3)
    const float SG2 = 6.74038866f;      // 2pi / 0.9^(2/3)
    u32 pw[16];
#pragma unroll
    for (int i = 0; i < 3; ++i) {
      float x = vd[i];
      float s0 = __sinf(x * SG0), c0 = __cosf(x * SG0);
      float s1 = __sinf(x * SG1), c1 = __cosf(x * SG1);
      float s2 = __sinf(x * SG2), c2 = __cosf(x * SG2);
      pw[i * 3 + 0] = (u32)f2h(s0) | ((u32)f2h(s1) << 16);
      pw[i * 3 + 1] = (u32)f2h(s2) | ((u32)f2h(c0) << 16);
      pw[i * 3 + 2] = (u32)f2h(c1) | ((u32)f2h(c2) << 16);
    }
#pragma unroll
    for (int q = 9; q < 16; ++q) pw[q] = 0u;   // zero-pad k = 18..31
    uint4* dst = (uint4*)&X[p * RS];
#pragma unroll
    for (int q = 0; q < 4; ++q)
      dst[q] = make_uint4(pw[4*q], pw[4*q+1], pw[4*q+2], pw[4*q+3]);
  }
  __syncthreads();

  const int xr[2] = { (pbase + r) * RS, (pbase + 16 + r) * RS };

  // ---- gather closure (used at li==2): embedding + renorm + bary -> X.
  // wave w owns px [w*16, w*16+16); 16-lane group g handles 4 of them.
  auto do_gather = [&]() {
#pragma unroll 4
    for (int i = 0; i < 4; ++i) {
      int p = w * 16 + g * 4 + i;
      size_t gp = bpix + p;
      const int*   vi = vert + gp * 3;
      const float* by = bary + gp * 3;
      f4 va = {0.f,0.f,0.f,0.f}, vb = {0.f,0.f,0.f,0.f};
#pragma unroll
      for (int vt = 0; vt < 3; ++vt) {
        int id = vi[vt] + 1;
        const float* row = emb + (size_t)id * 128 + r * 8;  // lane r: 8 chans
        f4 e0 = *(const f4*)row;
        f4 e1 = *(const f4*)(row + 4);
        float ss = e0[0]*e0[0] + e0[1]*e0[1] + e0[2]*e0[2] + e0[3]*e0[3]
                 + e1[0]*e1[0] + e1[1]*e1[1] + e1[2]*e1[2] + e1[3]*e1[3];
        ss += __shfl_xor(ss, 1);             // reduce within the 16-lane group
        ss += __shfl_xor(ss, 2);
        ss += __shfl_xor(ss, 4);
        ss += __shfl_xor(ss, 8);
        float nrm = sqrtf(ss);
        float sc  = (nrm > 1.f) ? (1.f / (nrm + 1e-7f)) : 1.f;  // torch max_norm
        float wt  = by[vt] * sc;
#pragma unroll
        for (int j = 0; j < 4; ++j) { va[j] += wt * e0[j]; vb[j] += wt * e1[j]; }
      }
      h8 o;
#pragma unroll
      for (int j = 0; j < 4; ++j) { o[j] = (_Float16)va[j]; o[j+4] = (_Float16)vb[j]; }
      *(h8*)&X[p * RS + r * 8] = o;
    }
  };

  // ---- vde (K=18 padded to 32): A from global; stage tile 0 meanwhile.
  STAGE(0);
  {
    h8 Av[4];
#pragma unroll
    for (int ntl = 0; ntl < 4; ++ntl)
      Av[ntl] = *(const h8*)&ws[(nbase + ntl * 16 + r) * PRS + g * 8];
    h8 pe[2];
#pragma unroll
    for (int t = 0; t < 2; ++t) pe[t] = *(const h8*)&X[xr[t] + g * 8];
    __syncthreads();   // pe in regs everywhere; DMA(0) drained; X now writable
#pragma unroll
    for (int ntl = 0; ntl < 4; ++ntl) {
      f4 bini = *(const f4*)&BL[nbase + ntl * 16 + 4 * g];
      const int col = nbase + ntl * 16 + 4 * g;
#pragma unroll
      for (int t = 0; t < 2; ++t) {
        f4 acc = MFMA16(Av[ntl], pe[t], bini, 0, 0, 0);
        *(uint2*)&X[xr[t] + col] =          // no relu on vde output
          make_uint2(pkrtz(acc[0], acc[1]), pkrtz(acc[2], acc[3]));
      }
    }
  }
  __syncthreads();   // X (vde out) coherent

  // ---- 11 full 128x128 layers, single WL buffer, staged per layer
  u32 vhp[2][4][2];   // captured vh: set at li==2, used at li==5
  LAYER(0);  LAYER(1);  LAYER(2);  LAYER(3);
  LAYER(4);  LAYER(5);  LAYER(6);  LAYER(7);
  LAYER(8);  LAYER(9);  LAYER(10);   // LAYER(10) stages j=11 (head tile)

  // ---- head_W2 (128 -> 4) + head_b2 from WL (channel-half-0 waves only)
  if (cg == 0) {
    h8 x[2][4];
#pragma unroll
    for (int t = 0; t < 2; ++t)
#pragma unroll
      for (int ks = 0; ks < 4; ++ks)
        x[t][ks] = *(const h8*)&X[xr[t] + ks * 32 + g * 8];
    f4 b2 = *(const f4*)&BL[1536 + 4 * g];   // g==0 lanes: real head_b2
    f4 acc[2] = {b2, b2};
#pragma unroll
    for (int ks = 0; ks < 4; ++ks) {
      h8 A = *(const h8*)&WL[r * 128 + ((ks * 32 + g * 8) ^ rsw)];
#pragma unroll
      for (int t = 0; t < 2; ++t)
        acc[t] = MFMA16(A, x[t][ks], acc[t], 0, 0, 0);
    }
    if (g == 0) {                      // lane r holds pixel r's rgba contiguously
#pragma unroll
      for (int t = 0; t < 2; ++t)
        *(f4*)&out[(bpix + pbase + t * 16 + r) * 4] = acc[t];
    }
  }
}

// ---------------------------------------------------------------------------
extern "C" void kernel_launch(void* const* d_in, const int* in_sizes, int n_in,
                              void* d_out, int out_size, void* d_ws, size_t ws_size,
                              hipStream_t stream) {
  const int*   vert    = (const int*)  d_in[0];
  const float* bary    = (const float*)d_in[1];
  const float* view    = (const float*)d_in[2];
  const float* emb     = (const float*)d_in[3];
  const float* vde_W   = (const float*)d_in[4];
  const float* vde_b   = (const float*)d_in[5];
  const float* vh_W    = (const float*)d_in[6];
  const float* vh_b    = (const float*)d_in[7];
  const float* hid_W   = (const float*)d_in[8];
  const float* hid_b   = (const float*)d_in[9];
  const float* head_W0 = (const float*)d_in[10];
  const float* head_b0 = (const float*)d_in[11];
  const float* head_W1 = (const float*)d_in[12];
  const float* head_b1 = (const float*)d_in[13];
  const float* head_W2 = (const float*)d_in[14];
  const float* head_b2 = (const float*)d_in[15];
  u16* wsp = (u16*)d_ws;   // needs 403456 B

  rc_prep<<<788, 256, 0, stream>>>(vde_W, vh_W, hid_W, head_W0, head_W1, head_W2, wsp);
  rc_main<<<4096, 512, 0, stream>>>(vert, bary, view, emb, vde_b, vh_b, hid_b,
                                    head_b0, head_b1, head_b2, wsp, (float*)d_out);
}

// Round 14
// 313.326 us; speedup vs baseline: 1.7015x; 1.1126x over previous
//
#include <hip/hip_runtime.h>

typedef unsigned int  u32;
typedef unsigned long long u64;
typedef unsigned short u16;
typedef __attribute__((ext_vector_type(8))) _Float16 h8;   // MFMA A/B frag: 8 fp16 = 4 VGPR
typedef __attribute__((ext_vector_type(2))) _Float16 h2;   // packed fp16 pair
typedef __attribute__((ext_vector_type(4))) float    f4;   // MFMA C/D frag

#define RS    136    // X row stride (fp16): 272B rows, 16B-aligned
#define PRS   40     // row stride for vde weights (K=18 padded to 32, stored 40)
#define PIXB  128    // pixels per block (4 px-groups x 32 px)
#define WOFF  5120   // vde region size (halves)
#define FULLT 16384  // one fragment-major weight tile (halves)
#define MFMA16 __builtin_amdgcn_mfma_f32_16x16x32_f16

__device__ __forceinline__ u16 f2h(float f) {
  _Float16 h = (_Float16)f;
  return __builtin_bit_cast(u16, h);
}
__device__ __forceinline__ u32 pkrtz(float a, float b) {
  return __builtin_bit_cast(u32, __builtin_amdgcn_cvt_pkrtz(a, b));
}
__device__ __forceinline__ u32 pkmul(u32 a, u32 b) {   // v_pk_mul_f16
  h2 r = __builtin_bit_cast(h2, a) * __builtin_bit_cast(h2, b);
  return __builtin_bit_cast(u32, r);
}
__device__ __forceinline__ u32 pkmax0(u32 a) {         // v_pk_max_f16 vs 0
  h2 z = {(_Float16)0.f, (_Float16)0.f};
  h2 r = __builtin_elementwise_max(__builtin_bit_cast(h2, a), z);
  return __builtin_bit_cast(u32, r);
}

// ---------------------------------------------------------------------------
// Prep: fp16 weights in FRAGMENT-MAJOR layout for coalesced A-frag loads.
// ws (halves): [0,5120) vdeT [128][40] (k<18 valid).
//   [5120 + j*16384), j=0..11: per tile, chunks [nt(8)][ks(4)][lane(64)][8]:
//   lane = g*16+r holds W[n = nt*16+r][k = ks*32+g*8 .. +7] — one
//   global_load_dwordx4 at (base + chunk*1024 + lane*16) IS the A-frag.
//   j: 0..2 vh, 3..8 hid, 9 headW0, 10 headW1, 11 headW2 (n>=4 zero)
// ---------------------------------------------------------------------------
__global__ __launch_bounds__(256) void rc_prep(
    const float* __restrict__ vde_W, const float* __restrict__ vh_W,
    const float* __restrict__ hid_W, const float* __restrict__ head_W0,
    const float* __restrict__ head_W1, const float* __restrict__ head_W2,
    u16* __restrict__ ws)
{
  const int TOT = WOFF + 12 * FULLT;   // 201728
  int i = blockIdx.x * 256 + threadIdx.x;
  if (i >= TOT) return;
  float val = 0.f;
  if (i < WOFF) {
    int n = i / PRS, k = i - n * PRS;
    if (k < 18) val = vde_W[k * 128 + n];
  } else {
    int t  = i - WOFF;
    int j  = t >> 14;          // tile
    int c  = t & 16383;
    int nt = c >> 11;          // output-channel tile
    int ks = (c >> 9) & 3;     // k-step
    int ln = (c >> 3) & 63;    // lane
    int e  = c & 7;            // element within frag
    int r  = ln & 15, g = ln >> 4;
    int n  = nt * 16 + r;
    int k  = ks * 32 + g * 8 + e;
    if (j < 3)        val = vh_W[j * 16384 + k * 128 + n];
    else if (j < 9)   val = hid_W[(j - 3) * 16384 + k * 128 + n];
    else if (j == 9)  val = head_W0[k * 128 + n];
    else if (j == 10) val = head_W1[k * 128 + n];
    else              val = (n < 4) ? head_W2[k * 4 + n] : 0.f;
  }
  ws[i] = f2h(val);
}

// ---------------------------------------------------------------------------
// Inline-asm weight loads (compiler cannot sink/reorder; waits are OURS —
// never rely on __syncthreads to drain asm loads, the compiler doesn't
// track them (R13 lesson)).
// ---------------------------------------------------------------------------
#define GLOAD(dst, base, voff, immstr)                                        \
  asm volatile("global_load_dwordx4 %0, %1, %2 offset:" immstr               \
               : "=v"(dst) : "v"(voff), "s"(base) : "memory")

#define ISSUE(S, NTL) do {                                                    \
  u32 vo_ = aoff + (NTL) * 4096;                                              \
  GLOAD(Ar##S[0], wbase, vo_, "0");                                           \
  GLOAD(Ar##S[1], wbase, vo_, "1024");                                        \
  GLOAD(Ar##S[2], wbase, vo_, "2048");                                        \
  GLOAD(Ar##S[3], wbase, vo_, "3072");                                        \
} while (0)

#define WAITV(nstr) do {                                                      \
  asm volatile("s_waitcnt vmcnt(" nstr ")" ::: "memory");                     \
  __builtin_amdgcn_sched_barrier(0);                                          \
} while (0)

// compute local channel tile NTL (2 pixel-tiles) from A-regs AA.
// epilogue: cvt_pkrtz -> packed relu -> [capture | pk_mul] -> ds_write_b64.
#define COMPUTE_NT(NTL, AA) do {                                              \
  f4 bini = *(const f4*)&BL[blb + nbase + (NTL) * 16 + 4 * g];                \
  f4 ac[2] = {bini, bini};                                                    \
  _Pragma("unroll")                                                           \
  for (int ks = 0; ks < 4; ++ks) {                                            \
    ac[0] = MFMA16(AA[ks], x[0][ks], ac[0], 0, 0, 0);                         \
    ac[1] = MFMA16(AA[ks], x[1][ks], ac[1], 0, 0, 0);                         \
  }                                                                           \
  const int col = nbase + (NTL) * 16 + 4 * g;                                 \
  _Pragma("unroll")                                                           \
  for (int t = 0; t < 2; ++t) {                                               \
    u32 lo = pkmax0(pkrtz(ac[t][0], ac[t][1]));                               \
    u32 hi = pkmax0(pkrtz(ac[t][2], ac[t][3]));                               \
    if (mode == 1) {                       /* capture vh (packed) */          \
      vhp[t][NTL][0] = lo; vhp[t][NTL][1] = hi;                               \
    } else {                                                                  \
      if (mode == 2) {                     /* h = relu(out) * vh */           \
        lo = pkmul(lo, vhp[t][NTL][0]);                                       \
        hi = pkmul(hi, vhp[t][NTL][1]);                                       \
      }                                                                       \
      *(uint2*)&X[xr[t] + col] = make_uint2(lo, hi);                          \
    }                                                                         \
  }                                                                           \
} while (0)

// one full 128x128 layer at 32px x 64ch per wave, weights via L1 asm ring.
// R7-proven counted-wait discipline: WAITV(8/8/4/0) before each compute,
// reissue into a slot only after computing from it.
// RACE NOTE (R11 lesson): waves (pg,0)/(pg,1) share pixel rows; the barrier
// between the x-reads and the first X write is REQUIRED.
#define LAYER(LI) do {                                                        \
  const int li   = (LI);                                                      \
  const int blb  = (li + 1) * 128;                                            \
  const int mode = (li == 2) ? 1 : (li == 5) ? 2 : 0;                         \
  const u64 wbase = (u64)(uintptr_t)(ws + WOFF + li * FULLT);                 \
  ISSUE(0, 0); ISSUE(1, 1); ISSUE(2, 2);   /* 12 loads in flight */           \
  h8 x[2][4];                                                                 \
  _Pragma("unroll")                                                           \
  for (int t = 0; t < 2; ++t)                                                 \
    _Pragma("unroll")                                                         \
    for (int ks = 0; ks < 4; ++ks)                                            \
      x[t][ks] = *(const h8*)&X[xr[t] + ks * 32 + g * 8];                     \
  __syncthreads();                 /* race barrier (X reads before writes) */ \
  WAITV("8");  COMPUTE_NT(0, Ar0);  ISSUE(0, 3);                              \
  WAITV("8");  COMPUTE_NT(1, Ar1);                                            \
  WAITV("4");  COMPUTE_NT(2, Ar2);                                            \
  WAITV("0");  COMPUTE_NT(3, Ar0);                                            \
  if (li == 2) { __syncthreads(); do_gather(); }                              \
  __syncthreads();                 /* publish X writes */                     \
} while (0)

// ---------------------------------------------------------------------------
// Main fused kernel — port-split: weights stream via L1 (asm ring, coalesced
// fragment loads), activations via LDS. LDS = X + biases only (41.5 KB) ->
// 2 blocks/CU at 512 thr; 8 waves = 4 px-groups (32 px) x 2 ch-halves (64 ch).
// ---------------------------------------------------------------------------
__global__ __launch_bounds__(512, 4) void rc_main(
    const int*   __restrict__ vert,  const float* __restrict__ bary,
    const float* __restrict__ view,  const float* __restrict__ emb,
    const float* __restrict__ vde_b, const float* __restrict__ vh_b,
    const float* __restrict__ hid_b, const float* __restrict__ head_b0,
    const float* __restrict__ head_b1, const float* __restrict__ head_b2,
    const u16*   __restrict__ ws,    float* __restrict__ out)
{
  __shared__ __align__(16) u16   X[PIXB * RS];   // 34816 B activations
  __shared__ __align__(16) float BL[1664];       // 6656 B: all biases

  const int tid  = threadIdx.x;
  const int lane = tid & 63;
  const int w    = tid >> 6;        // wave 0..7
  const int pg   = w >> 1;          // pixel group 0..3
  const int cg   = w & 1;           // channel half 0..1
  const int r    = lane & 15;       // pixel-within-tile; A row
  const int g    = lane >> 4;       // k-group; D row group
  const int pbase = pg * 32;        // wave's first pixel row (32 px/wave)
  const int nbase = cg * 64;        // wave's first output channel
  const u32 aoff  = (u32)(cg * 16384 + lane * 16);  // byte offset of frag chunk
  const size_t bpix = (size_t)blockIdx.x * PIXB;

  // ---- cooperative bias load into LDS
  for (int i = tid; i < 1664; i += 512) {
    float v;
    if      (i < 128)  v = vde_b[i];
    else if (i < 512)  v = vh_b[i - 128];
    else if (i < 1280) v = hid_b[i - 512];
    else if (i < 1408) v = head_b0[i - 1280];
    else if (i < 1536) v = head_b1[i - 1408];
    else if (i < 1540) v = head_b2[i - 1536];
    else               v = 0.f;
    BL[i] = v;
  }

  // ---- PE: threads 0..127 compute one pixel's encoding into X[row][0..32)
  if (tid < PIXB) {
    const int p = tid;
    const float* vd = view + (bpix + p) * 3;
    const float SG0 = 6.28318530718f;   // 2pi / 0.9^0
    const float SG1 = 6.50777324f;      // 2pi / 0.9^(1/3)
    const float SG2 = 6.74038866f;      // 2pi / 0.9^(2/3)
    u32 pw[16];
#pragma unroll
    for (int i = 0; i < 3; ++i) {
      float x = vd[i];
      float s0 = __sinf(x * SG0), c0 = __cosf(x * SG0);
      float s1 = __sinf(x * SG1), c1 = __cosf(x * SG1);
      float s2 = __sinf(x * SG2), c2 = __cosf(x * SG2);
      pw[i * 3 + 0] = (u32)f2h(s0) | ((u32)f2h(s1) << 16);
      pw[i * 3 + 1] = (u32)f2h(s2) | ((u32)f2h(c0) << 16);
      pw[i * 3 + 2] = (u32)f2h(c1) | ((u32)f2h(c2) << 16);
    }
#pragma unroll
    for (int q = 9; q < 16; ++q) pw[q] = 0u;   // zero-pad k = 18..31
    uint4* dst = (uint4*)&X[p * RS];
#pragma unroll
    for (int q = 0; q < 4; ++q)
      dst[q] = make_uint4(pw[4*q], pw[4*q+1], pw[4*q+2], pw[4*q+3]);
  }
  __syncthreads();

  const int xr[2] = { (pbase + r) * RS, (pbase + 16 + r) * RS };

  // ---- gather closure (used at li==2): embedding + renorm + bary -> X.
  // wave w owns px [w*16, w*16+16); 16-lane group g handles 4 of them.
  auto do_gather = [&]() {
#pragma unroll 4
    for (int i = 0; i < 4; ++i) {
      int p = w * 16 + g * 4 + i;
      size_t gp = bpix + p;
      const int*   vi = vert + gp * 3;
      const float* by = bary + gp * 3;
      f4 va = {0.f,0.f,0.f,0.f}, vb = {0.f,0.f,0.f,0.f};
#pragma unroll
      for (int vt = 0; vt < 3; ++vt) {
        int id = vi[vt] + 1;
        const float* row = emb + (size_t)id * 128 + r * 8;  // lane r: 8 chans
        f4 e0 = *(const f4*)row;
        f4 e1 = *(const f4*)(row + 4);
        float ss = e0[0]*e0[0] + e0[1]*e0[1] + e0[2]*e0[2] + e0[3]*e0[3]
                 + e1[0]*e1[0] + e1[1]*e1[1] + e1[2]*e1[2] + e1[3]*e1[3];
        ss += __shfl_xor(ss, 1);             // reduce within the 16-lane group
        ss += __shfl_xor(ss, 2);
        ss += __shfl_xor(ss, 4);
        ss += __shfl_xor(ss, 8);
        float nrm = sqrtf(ss);
        float sc  = (nrm > 1.f) ? (1.f / (nrm + 1e-7f)) : 1.f;  // torch max_norm
        float wt  = by[vt] * sc;
#pragma unroll
        for (int j = 0; j < 4; ++j) { va[j] += wt * e0[j]; vb[j] += wt * e1[j]; }
      }
      h8 o;
#pragma unroll
      for (int j = 0; j < 4; ++j) { o[j] = (_Float16)va[j]; o[j+4] = (_Float16)vb[j]; }
      *(h8*)&X[p * RS + r * 8] = o;
    }
  };

  // ---- vde (K=18 padded to 32): one-time, compiler-scheduled loads
  {
    h8 Av[4];
#pragma unroll
    for (int ntl = 0; ntl < 4; ++ntl)
      Av[ntl] = *(const h8*)&ws[(nbase + ntl * 16 + r) * PRS + g * 8];
    h8 pe[2];
#pragma unroll
    for (int t = 0; t < 2; ++t) pe[t] = *(const h8*)&X[xr[t] + g * 8];
    __syncthreads();   // pe in regs everywhere; X now writable
#pragma unroll
    for (int ntl = 0; ntl < 4; ++ntl) {
      f4 bini = *(const f4*)&BL[nbase + ntl * 16 + 4 * g];
      const int col = nbase + ntl * 16 + 4 * g;
#pragma unroll
      for (int t = 0; t < 2; ++t) {
        f4 acc = MFMA16(Av[ntl], pe[t], bini, 0, 0, 0);
        *(uint2*)&X[xr[t] + col] =          // no relu on vde output
          make_uint2(pkrtz(acc[0], acc[1]), pkrtz(acc[2], acc[3]));
      }
    }
  }
  __syncthreads();   // X (vde out) coherent

  // ---- 11 full 128x128 layers, weights via L1 asm ring
  u32 vhp[2][4][2];            // captured vh: set at li==2, used at li==5
  h8 Ar0[4], Ar1[4], Ar2[4];   // 3-slot ring (48 VGPRs)
  LAYER(0);  LAYER(1);  LAYER(2);  LAYER(3);
  LAYER(4);  LAYER(5);  LAYER(6);  LAYER(7);
  LAYER(8);  LAYER(9);  LAYER(10);

  // ---- head_W2 (128 -> 4) + head_b2 (fragment-major tile 11, nt=0)
  if (cg == 0) {
    h8 x[2][4];
#pragma unroll
    for (int t = 0; t < 2; ++t)
#pragma unroll
      for (int ks = 0; ks < 4; ++ks)
        x[t][ks] = *(const h8*)&X[xr[t] + ks * 32 + g * 8];
    const u16* wa = ws + WOFF + 11 * FULLT;
    f4 b2 = *(const f4*)&BL[1536 + 4 * g];   // g==0 lanes: real head_b2
    f4 acc[2] = {b2, b2};
#pragma unroll
    for (int ks = 0; ks < 4; ++ks) {
      h8 A = *(const h8*)&wa[ks * 512 + lane * 8];
#pragma unroll
      for (int t = 0; t < 2; ++t)
        acc[t] = MFMA16(A, x[t][ks], acc[t], 0, 0, 0);
    }
    if (g == 0) {                      // lane r holds pixel r's rgba contiguously
#pragma unroll
      for (int t = 0; t < 2; ++t)
        *(f4*)&out[(bpix + pbase + t * 16 + r) * 4] = acc[t];
    }
  }
}

// ---------------------------------------------------------------------------
extern "C" void kernel_launch(void* const* d_in, const int* in_sizes, int n_in,
                              void* d_out, int out_size, void* d_ws, size_t ws_size,
                              hipStream_t stream) {
  const int*   vert    = (const int*)  d_in[0];
  const float* bary    = (const float*)d_in[1];
  const float* view    = (const float*)d_in[2];
  const float* emb     = (const float*)d_in[3];
  const float* vde_W   = (const float*)d_in[4];
  const float* vde_b   = (const float*)d_in[5];
  const float* vh_W    = (const float*)d_in[6];
  const float* vh_b    = (const float*)d_in[7];
  const float* hid_W   = (const float*)d_in[8];
  const float* hid_b   = (const float*)d_in[9];
  const float* head_W0 = (const float*)d_in[10];
  const float* head_b0 = (const float*)d_in[11];
  const float* head_W1 = (const float*)d_in[12];
  const float* head_b1 = (const float*)d_in[13];
  const float* head_W2 = (const float*)d_in[14];
  const float* head_b2 = (const float*)d_in[15];
  u16* wsp = (u16*)d_ws;   // needs 403456 B

  rc_prep<<<788, 256, 0, stream>>>(vde_W, vh_W, hid_W, head_W0, head_W1, head_W2, wsp);
  rc_main<<<4096, 512, 0, stream>>>(vert, bary, view, emb, vde_b, vh_b, hid_b,
                                    head_b0, head_b1, head_b2, wsp, (float*)d_out);
}

// Round 16
// 312.759 us; speedup vs baseline: 1.7046x; 1.0018x over previous
//
#include <hip/hip_runtime.h>

typedef unsigned int  u32;
typedef unsigned long long u64;
typedef unsigned short u16;
typedef __attribute__((ext_vector_type(8))) _Float16 h8;   // MFMA A/B frag: 8 fp16 = 4 VGPR
typedef __attribute__((ext_vector_type(2))) _Float16 h2;   // packed fp16 pair
typedef __attribute__((ext_vector_type(4))) float    f4;   // MFMA C/D frag

#define RS    136    // X row stride (fp16): 272B rows, 16B-aligned
#define PRS   40     // row stride for vde weights (K=18 padded to 32, stored 40)
#define PIXB  128    // pixels per block (4 px-groups x 32 px)
#define WOFF  5120   // vde region size (halves)
#define FULLT 16384  // one fragment-major weight tile (halves)
#define MFMA16 __builtin_amdgcn_mfma_f32_16x16x32_f16

__device__ __forceinline__ u16 f2h(float f) {
  _Float16 h = (_Float16)f;
  return __builtin_bit_cast(u16, h);
}
__device__ __forceinline__ u32 pkrtz(float a, float b) {
  return __builtin_bit_cast(u32, __builtin_amdgcn_cvt_pkrtz(a, b));
}
__device__ __forceinline__ u32 pkmul(u32 a, u32 b) {   // v_pk_mul_f16
  h2 r = __builtin_bit_cast(h2, a) * __builtin_bit_cast(h2, b);
  return __builtin_bit_cast(u32, r);
}
__device__ __forceinline__ u32 pkmax0(u32 a) {         // v_pk_max_f16 vs 0
  h2 z = {(_Float16)0.f, (_Float16)0.f};
  h2 r = __builtin_elementwise_max(__builtin_bit_cast(h2, a), z);
  return __builtin_bit_cast(u32, r);
}

// ---------------------------------------------------------------------------
// Prep: fp16 weights in FRAGMENT-MAJOR layout for coalesced A-frag loads.
// ws (halves): [0,5120) vdeT [128][40] (k<18 valid).
//   [5120 + j*16384), j=0..11: per tile, chunks [nt(8)][ks(4)][lane(64)][8]:
//   lane = g*16+r holds W[n = nt*16+r][k = ks*32+g*8 .. +7] — one
//   global_load_dwordx4 at (base + chunk*1024 + lane*16) IS the A-frag.
//   j: 0..2 vh, 3..8 hid, 9 headW0, 10 headW1, 11 headW2 (n>=4 zero)
// ---------------------------------------------------------------------------
__global__ __launch_bounds__(256) void rc_prep(
    const float* __restrict__ vde_W, const float* __restrict__ vh_W,
    const float* __restrict__ hid_W, const float* __restrict__ head_W0,
    const float* __restrict__ head_W1, const float* __restrict__ head_W2,
    u16* __restrict__ ws)
{
  const int TOT = WOFF + 12 * FULLT;   // 201728
  int i = blockIdx.x * 256 + threadIdx.x;
  if (i >= TOT) return;
  float val = 0.f;
  if (i < WOFF) {
    int n = i / PRS, k = i - n * PRS;
    if (k < 18) val = vde_W[k * 128 + n];
  } else {
    int t  = i - WOFF;
    int j  = t >> 14;          // tile
    int c  = t & 16383;
    int nt = c >> 11;          // output-channel tile
    int ks = (c >> 9) & 3;     // k-step
    int ln = (c >> 3) & 63;    // lane
    int e  = c & 7;            // element within frag
    int r  = ln & 15, g = ln >> 4;
    int n  = nt * 16 + r;
    int k  = ks * 32 + g * 8 + e;
    if (j < 3)        val = vh_W[j * 16384 + k * 128 + n];
    else if (j < 9)   val = hid_W[(j - 3) * 16384 + k * 128 + n];
    else if (j == 9)  val = head_W0[k * 128 + n];
    else if (j == 10) val = head_W1[k * 128 + n];
    else              val = (n < 4) ? head_W2[k * 4 + n] : 0.f;
  }
  ws[i] = f2h(val);
}

// ---------------------------------------------------------------------------
// Inline-asm weight loads. HARD RULES (R13/R15 aborts): every issued load is
// consumed via a counted WAITV within the SAME layer body; nothing is ever
// in flight across __syncthreads, the gather, or kernel exit.
// ---------------------------------------------------------------------------
#define GLOAD(dst, base, voff, immstr)                                        \
  asm volatile("global_load_dwordx4 %0, %1, %2 offset:" immstr               \
               : "=v"(dst) : "v"(voff), "s"(base) : "memory")

#define ISSUE(S, NTL) do {                                                    \
  u32 vo_ = aoff + (NTL) * 4096;                                              \
  GLOAD(Ar##S[0], wbase, vo_, "0");                                           \
  GLOAD(Ar##S[1], wbase, vo_, "1024");                                        \
  GLOAD(Ar##S[2], wbase, vo_, "2048");                                        \
  GLOAD(Ar##S[3], wbase, vo_, "3072");                                        \
} while (0)

#define WAITV(nstr) do {                                                      \
  asm volatile("s_waitcnt vmcnt(" nstr ")" ::: "memory");                     \
  __builtin_amdgcn_sched_barrier(0);                                          \
} while (0)

// compute local channel tile NTL (2 pixel-tiles) from A-regs AA; write XNB.
// epilogue: cvt_pkrtz -> packed relu -> [capture | pk_mul] -> ds_write_b64.
#define COMPUTE_NT(NTL, AA, XNB) do {                                         \
  f4 bini = *(const f4*)&BL[blb + nbase + (NTL) * 16 + 4 * g];                \
  f4 ac[2] = {bini, bini};                                                    \
  _Pragma("unroll")                                                           \
  for (int ks = 0; ks < 4; ++ks) {                                            \
    ac[0] = MFMA16(AA[ks], x[0][ks], ac[0], 0, 0, 0);                         \
    ac[1] = MFMA16(AA[ks], x[1][ks], ac[1], 0, 0, 0);                         \
  }                                                                           \
  const int col = nbase + (NTL) * 16 + 4 * g;                                 \
  _Pragma("unroll")                                                           \
  for (int t = 0; t < 2; ++t) {                                               \
    u32 lo = pkmax0(pkrtz(ac[t][0], ac[t][1]));                               \
    u32 hi = pkmax0(pkrtz(ac[t][2], ac[t][3]));                               \
    if (mode == 1) {                       /* capture vh (packed) */          \
      vhp[t][NTL][0] = lo; vhp[t][NTL][1] = hi;                               \
    } else {                                                                  \
      if (mode == 2) {                     /* h = relu(out) * vh */           \
        lo = pkmul(lo, vhp[t][NTL][0]);                                       \
        hi = pkmul(hi, vhp[t][NTL][1]);                                       \
      }                                                                       \
      *(uint2*)&XNB[xr[t] + col] = make_uint2(lo, hi);                        \
    }                                                                         \
  }                                                                           \
} while (0)

// one full 128x128 layer at 32px x 64ch per wave, ping-pong X (XC -> XN):
// separate read/write buffers -> no intra-layer race -> ONE barrier/layer.
// Load discipline identical to R14 (proven): 12 issued up front, slot3
// reissued after C0, all drained by the WAITV("0") before C3.
#define LAYER(LI, XC, XN) do {                                                \
  const int li   = (LI);                                                      \
  const int blb  = (li + 1) * 128;                                            \
  const int mode = (li == 2) ? 1 : (li == 5) ? 2 : 0;                         \
  const u64 wbase = (u64)(uintptr_t)(ws + WOFF + li * FULLT);                 \
  ISSUE(0, 0); ISSUE(1, 1); ISSUE(2, 2);   /* 12 loads in flight */           \
  h8 x[2][4];                                                                 \
  _Pragma("unroll")                                                           \
  for (int t = 0; t < 2; ++t)                                                 \
    _Pragma("unroll")                                                         \
    for (int ks = 0; ks < 4; ++ks)                                            \
      x[t][ks] = *(const h8*)&XC[xr[t] + ks * 32 + g * 8];                    \
  WAITV("8");  COMPUTE_NT(0, Ar0, XN);  ISSUE(0, 3);                          \
  WAITV("8");  COMPUTE_NT(1, Ar1, XN);                                        \
  WAITV("4");  COMPUTE_NT(2, Ar2, XN);                                        \
  WAITV("0");  COMPUTE_NT(3, Ar0, XN);   /* all asm loads drained here */     \
  if (li == 2) do_gather(XN);                                                 \
  __syncthreads();                 /* publish XN for next layer */            \
} while (0)

// ---------------------------------------------------------------------------
// Main fused kernel — port-split (weights via L1 fragment-major asm ring,
// activations via LDS) + X ping-pong: X0/X1 + biases = 76.3 KB -> 2 blocks/CU
// at 512 thr; 8 waves = 4 px-groups (32 px) x 2 ch-halves (64 ch).
// One barrier per layer; no asm load ever crosses a barrier.
// ---------------------------------------------------------------------------
__global__ __launch_bounds__(512, 4) void rc_main(
    const int*   __restrict__ vert,  const float* __restrict__ bary,
    const float* __restrict__ view,  const float* __restrict__ emb,
    const float* __restrict__ vde_b, const float* __restrict__ vh_b,
    const float* __restrict__ hid_b, const float* __restrict__ head_b0,
    const float* __restrict__ head_b1, const float* __restrict__ head_b2,
    const u16*   __restrict__ ws,    float* __restrict__ out)
{
  __shared__ __align__(16) u16   X0[PIXB * RS];  // 34816 B activations (ping)
  __shared__ __align__(16) u16   X1[PIXB * RS];  // 34816 B activations (pong)
  __shared__ __align__(16) float BL[1664];       // 6656 B: all biases

  const int tid  = threadIdx.x;
  const int lane = tid & 63;
  const int w    = tid >> 6;        // wave 0..7
  const int pg   = w >> 1;          // pixel group 0..3
  const int cg   = w & 1;           // channel half 0..1
  const int r    = lane & 15;       // pixel-within-tile; A row
  const int g    = lane >> 4;       // k-group; D row group
  const int pbase = pg * 32;        // wave's first pixel row (32 px/wave)
  const int nbase = cg * 64;        // wave's first output channel
  const u32 aoff  = (u32)(cg * 16384 + lane * 16);  // byte offset of frag chunk
  const size_t bpix = (size_t)blockIdx.x * PIXB;

  // ---- cooperative bias load into LDS
  for (int i = tid; i < 1664; i += 512) {
    float v;
    if      (i < 128)  v = vde_b[i];
    else if (i < 512)  v = vh_b[i - 128];
    else if (i < 1280) v = hid_b[i - 512];
    else if (i < 1408) v = head_b0[i - 1280];
    else if (i < 1536) v = head_b1[i - 1408];
    else if (i < 1540) v = head_b2[i - 1536];
    else               v = 0.f;
    BL[i] = v;
  }

  // ---- PE: threads 0..127 compute one pixel's encoding into X0[row][0..32)
  if (tid < PIXB) {
    const int p = tid;
    const float* vd = view + (bpix + p) * 3;
    const float SG0 = 6.28318530718f;   // 2pi / 0.9^0
    const float SG1 = 6.50777324f;      // 2pi / 0.9^(1/3)
    const float SG2 = 6.74038866f;      // 2pi / 0.9^(2/3)
    u32 pw[16];
#pragma unroll
    for (int i = 0; i < 3; ++i) {
      float x = vd[i];
      float s0 = __sinf(x * SG0), c0 = __cosf(x * SG0);
      float s1 = __sinf(x * SG1), c1 = __cosf(x * SG1);
      float s2 = __sinf(x * SG2), c2 = __cosf(x * SG2);
      pw[i * 3 + 0] = (u32)f2h(s0) | ((u32)f2h(s1) << 16);
      pw[i * 3 + 1] = (u32)f2h(s2) | ((u32)f2h(c0) << 16);
      pw[i * 3 + 2] = (u32)f2h(c1) | ((u32)f2h(c2) << 16);
    }
#pragma unroll
    for (int q = 9; q < 16; ++q) pw[q] = 0u;   // zero-pad k = 18..31
    uint4* dst = (uint4*)&X0[p * RS];
#pragma unroll
    for (int q = 0; q < 4; ++q)
      dst[q] = make_uint4(pw[4*q], pw[4*q+1], pw[4*q+2], pw[4*q+3]);
  }
  __syncthreads();   // PE (X0) published

  const int xr[2] = { (pbase + r) * RS, (pbase + 16 + r) * RS };

  // ---- gather closure (used at li==2): embedding + renorm + bary -> XN.
  // wave w owns px [w*16, w*16+16); 16-lane group g handles 4 of them.
  auto do_gather = [&](u16* XNB) {
#pragma unroll 4
    for (int i = 0; i < 4; ++i) {
      int p = w * 16 + g * 4 + i;
      size_t gp = bpix + p;
      const int*   vi = vert + gp * 3;
      const float* by = bary + gp * 3;
      f4 va = {0.f,0.f,0.f,0.f}, vb = {0.f,0.f,0.f,0.f};
#pragma unroll
      for (int vt = 0; vt < 3; ++vt) {
        int id = vi[vt] + 1;
        const float* row = emb + (size_t)id * 128 + r * 8;  // lane r: 8 chans
        f4 e0 = *(const f4*)row;
        f4 e1 = *(const f4*)(row + 4);
        float ss = e0[0]*e0[0] + e0[1]*e0[1] + e0[2]*e0[2] + e0[3]*e0[3]
                 + e1[0]*e1[0] + e1[1]*e1[1] + e1[2]*e1[2] + e1[3]*e1[3];
        ss += __shfl_xor(ss, 1);             // reduce within the 16-lane group
        ss += __shfl_xor(ss, 2);
        ss += __shfl_xor(ss, 4);
        ss += __shfl_xor(ss, 8);
        float nrm = sqrtf(ss);
        float sc  = (nrm > 1.f) ? (1.f / (nrm + 1e-7f)) : 1.f;  // torch max_norm
        float wt  = by[vt] * sc;
#pragma unroll
        for (int j = 0; j < 4; ++j) { va[j] += wt * e0[j]; vb[j] += wt * e1[j]; }
      }
      h8 o;
#pragma unroll
      for (int j = 0; j < 4; ++j) { o[j] = (_Float16)va[j]; o[j+4] = (_Float16)vb[j]; }
      *(h8*)&XNB[p * RS + r * 8] = o;
    }
  };

  // ---- vde (K=18 padded to 32): X0 (PE) -> X1, compiler-scheduled loads
  {
    h8 Av[4];
#pragma unroll
    for (int ntl = 0; ntl < 4; ++ntl)
      Av[ntl] = *(const h8*)&ws[(nbase + ntl * 16 + r) * PRS + g * 8];
    h8 pe[2];
#pragma unroll
    for (int t = 0; t < 2; ++t) pe[t] = *(const h8*)&X0[xr[t] + g * 8];
#pragma unroll
    for (int ntl = 0; ntl < 4; ++ntl) {
      f4 bini = *(const f4*)&BL[nbase + ntl * 16 + 4 * g];
      const int col = nbase + ntl * 16 + 4 * g;
#pragma unroll
      for (int t = 0; t < 2; ++t) {
        f4 acc = MFMA16(Av[ntl], pe[t], bini, 0, 0, 0);
        *(uint2*)&X1[xr[t] + col] =         // no relu on vde output
          make_uint2(pkrtz(acc[0], acc[1]), pkrtz(acc[2], acc[3]));
      }
    }
  }
  __syncthreads();   // X1 (vde out) published

  // ---- 11 full 128x128 layers, ping-pong: X1->X0->X1->...
  u32 vhp[2][4][2];            // captured vh: set at li==2, used at li==5
  h8 Ar0[4], Ar1[4], Ar2[4];   // 3-slot ring (48 VGPRs)
  LAYER(0, X1, X0);  LAYER(1, X0, X1);
  LAYER(2, X1, X0);  LAYER(3, X0, X1);   // li==2: vh capture + gather -> X0
  LAYER(4, X1, X0);  LAYER(5, X0, X1);
  LAYER(6, X1, X0);  LAYER(7, X0, X1);
  LAYER(8, X1, X0);  LAYER(9, X0, X1);
  LAYER(10, X1, X0);

  // ---- head_W2 (128 -> 4) + head_b2 from X0; compiler-scheduled weights
  if (cg == 0) {
    h8 x[2][4];
#pragma unroll
    for (int t = 0; t < 2; ++t)
#pragma unroll
      for (int ks = 0; ks < 4; ++ks)
        x[t][ks] = *(const h8*)&X0[xr[t] + ks * 32 + g * 8];
    const u16* wa = ws + WOFF + 11 * FULLT;
    f4 b2 = *(const f4*)&BL[1536 + 4 * g];   // g==0 lanes: real head_b2
    f4 acc[2] = {b2, b2};
#pragma unroll
    for (int ks = 0; ks < 4; ++ks) {
      h8 A = *(const h8*)&wa[ks * 512 + lane * 8];
#pragma unroll
      for (int t = 0; t < 2; ++t)
        acc[t] = MFMA16(A, x[t][ks], acc[t], 0, 0, 0);
    }
    if (g == 0) {                      // lane r holds pixel r's rgba contiguously
#pragma unroll
      for (int t = 0; t < 2; ++t)
        *(f4*)&out[(bpix + pbase + t * 16 + r) * 4] = acc[t];
    }
  }
}

// ---------------------------------------------------------------------------
extern "C" void kernel_launch(void* const* d_in, const int* in_sizes, int n_in,
                              void* d_out, int out_size, void* d_ws, size_t ws_size,
                              hipStream_t stream) {
  const int*   vert    = (const int*)  d_in[0];
  const float* bary    = (const float*)d_in[1];
  const float* view    = (const float*)d_in[2];
  const float* emb     = (const float*)d_in[3];
  const float* vde_W   = (const float*)d_in[4];
  const float* vde_b   = (const float*)d_in[5];
  const float* vh_W    = (const float*)d_in[6];
  const float* vh_b    = (const float*)d_in[7];
  const float* hid_W   = (const float*)d_in[8];
  const float* hid_b   = (const float*)d_in[9];
  const float* head_W0 = (const float*)d_in[10];
  const float* head_b0 = (const float*)d_in[11];
  const float* head_W1 = (const float*)d_in[12];
  const float* head_b1 = (const float*)d_in[13];
  const float* head_W2 = (const float*)d_in[14];
  const float* head_b2 = (const float*)d_in[15];
  u16* wsp = (u16*)d_ws;   // needs 403456 B

  rc_prep<<<788, 256, 0, stream>>>(vde_W, vh_W, hid_W, head_W0, head_W1, head_W2, wsp);
  rc_main<<<4096, 512, 0, stream>>>(vert, bary, view, emb, vde_b, vh_b, hid_b,
                                    head_b0, head_b1, head_b2, wsp, (float*)d_out);
}

// Round 17
// 312.072 us; speedup vs baseline: 1.7083x; 1.0022x over previous
//
#include <hip/hip_runtime.h>

typedef unsigned int  u32;
typedef unsigned long long u64;
typedef unsigned short u16;
typedef __attribute__((ext_vector_type(8))) _Float16 h8;   // MFMA A/B frag: 8 fp16 = 4 VGPR
typedef __attribute__((ext_vector_type(2))) _Float16 h2;   // packed fp16 pair
typedef __attribute__((ext_vector_type(4))) float    f4;   // MFMA C/D frag

#define RS    136    // X row stride (fp16): 272B rows, 16B-aligned
#define PRS   40     // row stride for vde weights (K=18 padded to 32, stored 40)
#define PIXB  128    // pixels per block (4 px-groups x 32 px)
#define WOFF  5120   // vde region size (halves)
#define FULLT 16384  // one fragment-major weight tile (halves)
#define MFMA16 __builtin_amdgcn_mfma_f32_16x16x32_f16

__device__ __forceinline__ u16 f2h(float f) {
  _Float16 h = (_Float16)f;
  return __builtin_bit_cast(u16, h);
}
__device__ __forceinline__ u32 pkrtz(float a, float b) {
  return __builtin_bit_cast(u32, __builtin_amdgcn_cvt_pkrtz(a, b));
}
__device__ __forceinline__ u32 pkmul(u32 a, u32 b) {   // v_pk_mul_f16
  h2 r = __builtin_bit_cast(h2, a) * __builtin_bit_cast(h2, b);
  return __builtin_bit_cast(u32, r);
}
__device__ __forceinline__ u32 pkmax0(u32 a) {         // v_pk_max_f16 vs 0
  h2 z = {(_Float16)0.f, (_Float16)0.f};
  h2 r = __builtin_elementwise_max(__builtin_bit_cast(h2, a), z);
  return __builtin_bit_cast(u32, r);
}

// ---------------------------------------------------------------------------
// Prep: fp16 weights in FRAGMENT-MAJOR layout for coalesced A-frag loads.
// ws (halves): [0,5120) vdeT [128][40] (k<18 valid).
//   [5120 + j*16384), j=0..11: per tile, chunks [nt(8)][ks(4)][lane(64)][8]:
//   lane = g*16+r holds W[n = nt*16+r][k = ks*32+g*8 .. +7] — one
//   global_load_dwordx4 at (base + chunk*1024 + lane*16) IS the A-frag.
//   j: 0..2 vh, 3..8 hid, 9 headW0, 10 headW1, 11 headW2 (n>=4 zero)
// ---------------------------------------------------------------------------
__global__ __launch_bounds__(256) void rc_prep(
    const float* __restrict__ vde_W, const float* __restrict__ vh_W,
    const float* __restrict__ hid_W, const float* __restrict__ head_W0,
    const float* __restrict__ head_W1, const float* __restrict__ head_W2,
    u16* __restrict__ ws)
{
  const int TOT = WOFF + 12 * FULLT;   // 201728
  int i = blockIdx.x * 256 + threadIdx.x;
  if (i >= TOT) return;
  float val = 0.f;
  if (i < WOFF) {
    int n = i / PRS, k = i - n * PRS;
    if (k < 18) val = vde_W[k * 128 + n];
  } else {
    int t  = i - WOFF;
    int j  = t >> 14;          // tile
    int c  = t & 16383;
    int nt = c >> 11;          // output-channel tile
    int ks = (c >> 9) & 3;     // k-step
    int ln = (c >> 3) & 63;    // lane
    int e  = c & 7;            // element within frag
    int r  = ln & 15, g = ln >> 4;
    int n  = nt * 16 + r;
    int k  = ks * 32 + g * 8 + e;
    if (j < 3)        val = vh_W[j * 16384 + k * 128 + n];
    else if (j < 9)   val = hid_W[(j - 3) * 16384 + k * 128 + n];
    else if (j == 9)  val = head_W0[k * 128 + n];
    else if (j == 10) val = head_W1[k * 128 + n];
    else              val = (n < 4) ? head_W2[k * 4 + n] : 0.f;
  }
  ws[i] = f2h(val);
}

// ---------------------------------------------------------------------------
// Inline-asm weight loads. HARD RULES (R13/R15 aborts): every issued load is
// consumed via a counted WAITV within the SAME layer body; nothing is ever
// in flight across __syncthreads, the gather, or kernel exit.
// ---------------------------------------------------------------------------
#define GLOAD(dst, base, voff, immstr)                                        \
  asm volatile("global_load_dwordx4 %0, %1, %2 offset:" immstr               \
               : "=v"(dst) : "v"(voff), "s"(base) : "memory")

#define ISSUE(S, NTL) do {                                                    \
  u32 vo_ = aoff + (NTL) * 4096;                                              \
  GLOAD(Ar##S[0], wbase, vo_, "0");                                           \
  GLOAD(Ar##S[1], wbase, vo_, "1024");                                        \
  GLOAD(Ar##S[2], wbase, vo_, "2048");                                        \
  GLOAD(Ar##S[3], wbase, vo_, "3072");                                        \
} while (0)

#define WAITV(nstr) do {                                                      \
  asm volatile("s_waitcnt vmcnt(" nstr ")" ::: "memory");                     \
  __builtin_amdgcn_sched_barrier(0);                                          \
} while (0)

// compute local channel tile NTL (2 pixel-tiles) from A-regs AA; write XNB.
// epilogue: cvt_pkrtz -> packed relu -> [capture | pk_mul] -> ds_write_b64.
#define COMPUTE_NT(NTL, AA, XNB) do {                                         \
  f4 bini = *(const f4*)&BL[blb + nbase + (NTL) * 16 + 4 * g];                \
  f4 ac[2] = {bini, bini};                                                    \
  _Pragma("unroll")                                                           \
  for (int ks = 0; ks < 4; ++ks) {                                            \
    ac[0] = MFMA16(AA[ks], x[0][ks], ac[0], 0, 0, 0);                         \
    ac[1] = MFMA16(AA[ks], x[1][ks], ac[1], 0, 0, 0);                         \
  }                                                                           \
  const int col = nbase + (NTL) * 16 + 4 * g;                                 \
  _Pragma("unroll")                                                           \
  for (int t = 0; t < 2; ++t) {                                               \
    u32 lo = pkmax0(pkrtz(ac[t][0], ac[t][1]));                               \
    u32 hi = pkmax0(pkrtz(ac[t][2], ac[t][3]));                               \
    if (mode == 1) {                       /* capture vh (packed) */          \
      vhp[t][NTL][0] = lo; vhp[t][NTL][1] = hi;                               \
    } else {                                                                  \
      if (mode == 2) {                     /* h = relu(out) * vh */           \
        lo = pkmul(lo, vhp[t][NTL][0]);                                       \
        hi = pkmul(hi, vhp[t][NTL][1]);                                       \
      }                                                                       \
      *(uint2*)&XNB[xr[t] + col] = make_uint2(lo, hi);                        \
    }                                                                         \
  }                                                                           \
} while (0)

// one full 128x128 layer at 32px x 64ch per wave, ping-pong X (XC -> XN):
// separate read/write buffers -> no intra-layer race -> ONE barrier/layer.
// Load discipline identical to R14 (proven): 12 issued up front, slot3
// reissued after C0, all drained by the WAITV("0") before C3.
#define LAYER(LI, XC, XN) do {                                                \
  const int li   = (LI);                                                      \
  const int blb  = (li + 1) * 128;                                            \
  const int mode = (li == 2) ? 1 : (li == 5) ? 2 : 0;                         \
  const u64 wbase = (u64)(uintptr_t)(ws + WOFF + li * FULLT);                 \
  ISSUE(0, 0); ISSUE(1, 1); ISSUE(2, 2);   /* 12 loads in flight */           \
  h8 x[2][4];                                                                 \
  _Pragma("unroll")                                                           \
  for (int t = 0; t < 2; ++t)                                                 \
    _Pragma("unroll")                                                         \
    for (int ks = 0; ks < 4; ++ks)                                            \
      x[t][ks] = *(const h8*)&XC[xr[t] + ks * 32 + g * 8];                    \
  WAITV("8");  COMPUTE_NT(0, Ar0, XN);  ISSUE(0, 3);                          \
  WAITV("8");  COMPUTE_NT(1, Ar1, XN);                                        \
  WAITV("4");  COMPUTE_NT(2, Ar2, XN);                                        \
  WAITV("0");  COMPUTE_NT(3, Ar0, XN);   /* all asm loads drained here */     \
  if (li == 2) do_gather(XN);                                                 \
  __syncthreads();                 /* publish XN for next layer */            \
} while (0)

// ---------------------------------------------------------------------------
// Main fused kernel — port-split (weights via L1 fragment-major asm ring,
// activations via LDS) + X ping-pong: X0/X1 + biases = 76.3 KB -> 2 blocks/CU
// at 512 thr; 8 waves = 4 px-groups (32 px) x 2 ch-halves (64 ch).
// One barrier per layer; no asm load ever crosses a barrier.
// ---------------------------------------------------------------------------
__global__ __launch_bounds__(512, 4) void rc_main(
    const int*   __restrict__ vert,  const float* __restrict__ bary,
    const float* __restrict__ view,  const float* __restrict__ emb,
    const float* __restrict__ vde_b, const float* __restrict__ vh_b,
    const float* __restrict__ hid_b, const float* __restrict__ head_b0,
    const float* __restrict__ head_b1, const float* __restrict__ head_b2,
    const u16*   __restrict__ ws,    float* __restrict__ out)
{
  __shared__ __align__(16) u16   X0[PIXB * RS];  // 34816 B activations (ping)
  __shared__ __align__(16) u16   X1[PIXB * RS];  // 34816 B activations (pong)
  __shared__ __align__(16) float BL[1664];       // 6656 B: all biases

  const int tid  = threadIdx.x;
  const int lane = tid & 63;
  const int w    = tid >> 6;        // wave 0..7
  const int pg   = w >> 1;          // pixel group 0..3
  const int cg   = w & 1;           // channel half 0..1
  const int r    = lane & 15;       // pixel-within-tile; A row
  const int g    = lane >> 4;       // k-group; D row group
  const int pbase = pg * 32;        // wave's first pixel row (32 px/wave)
  const int nbase = cg * 64;        // wave's first output channel
  const u32 aoff  = (u32)(cg * 16384 + lane * 16);  // byte offset of frag chunk
  const size_t bpix = (size_t)blockIdx.x * PIXB;

  // ---- cooperative bias load into LDS
  for (int i = tid; i < 1664; i += 512) {
    float v;
    if      (i < 128)  v = vde_b[i];
    else if (i < 512)  v = vh_b[i - 128];
    else if (i < 1280) v = hid_b[i - 512];
    else if (i < 1408) v = head_b0[i - 1280];
    else if (i < 1536) v = head_b1[i - 1408];
    else if (i < 1540) v = head_b2[i - 1536];
    else               v = 0.f;
    BL[i] = v;
  }

  // ---- PE: threads 0..127 compute one pixel's encoding into X0[row][0..32)
  if (tid < PIXB) {
    const int p = tid;
    const float* vd = view + (bpix + p) * 3;
    const float SG0 = 6.28318530718f;   // 2pi / 0.9^0
    const float SG1 = 6.50777324f;      // 2pi / 0.9^(1/3)
    const float SG2 = 6.74038866f;      // 2pi / 0.9^(2/3)
    u32 pw[16];
#pragma unroll
    for (int i = 0; i < 3; ++i) {
      float x = vd[i];
      float s0 = __sinf(x * SG0), c0 = __cosf(x * SG0);
      float s1 = __sinf(x * SG1), c1 = __cosf(x * SG1);
      float s2 = __sinf(x * SG2), c2 = __cosf(x * SG2);
      pw[i * 3 + 0] = (u32)f2h(s0) | ((u32)f2h(s1) << 16);
      pw[i * 3 + 1] = (u32)f2h(s2) | ((u32)f2h(c0) << 16);
      pw[i * 3 + 2] = (u32)f2h(c1) | ((u32)f2h(c2) << 16);
    }
#pragma unroll
    for (int q = 9; q < 16; ++q) pw[q] = 0u;   // zero-pad k = 18..31
    uint4* dst = (uint4*)&X0[p * RS];
#pragma unroll
    for (int q = 0; q < 4; ++q)
      dst[q] = make_uint4(pw[4*q], pw[4*q+1], pw[4*q+2], pw[4*q+3]);
  }
  __syncthreads();   // PE (X0) published

  const int xr[2] = { (pbase + r) * RS, (pbase + 16 + r) * RS };

  // ---- gather closure (used at li==2): embedding + renorm + bary -> XN.
  // wave w owns px [w*16, w*16+16); 16-lane group g handles 4 of them.
  auto do_gather = [&](u16* XNB) {
#pragma unroll 4
    for (int i = 0; i < 4; ++i) {
      int p = w * 16 + g * 4 + i;
      size_t gp = bpix + p;
      const int*   vi = vert + gp * 3;
      const float* by = bary + gp * 3;
      f4 va = {0.f,0.f,0.f,0.f}, vb = {0.f,0.f,0.f,0.f};
#pragma unroll
      for (int vt = 0; vt < 3; ++vt) {
        int id = vi[vt] + 1;
        const float* row = emb + (size_t)id * 128 + r * 8;  // lane r: 8 chans
        f4 e0 = *(const f4*)row;
        f4 e1 = *(const f4*)(row + 4);
        float ss = e0[0]*e0[0] + e0[1]*e0[1] + e0[2]*e0[2] + e0[3]*e0[3]
                 + e1[0]*e1[0] + e1[1]*e1[1] + e1[2]*e1[2] + e1[3]*e1[3];
        ss += __shfl_xor(ss, 1);             // reduce within the 16-lane group
        ss += __shfl_xor(ss, 2);
        ss += __shfl_xor(ss, 4);
        ss += __shfl_xor(ss, 8);
        float nrm = sqrtf(ss);
        float sc  = (nrm > 1.f) ? (1.f / (nrm + 1e-7f)) : 1.f;  // torch max_norm
        float wt  = by[vt] * sc;
#pragma unroll
        for (int j = 0; j < 4; ++j) { va[j] += wt * e0[j]; vb[j] += wt * e1[j]; }
      }
      h8 o;
#pragma unroll
      for (int j = 0; j < 4; ++j) { o[j] = (_Float16)va[j]; o[j+4] = (_Float16)vb[j]; }
      *(h8*)&XNB[p * RS + r * 8] = o;
    }
  };

  // ---- vde (K=18 padded to 32): X0 (PE) -> X1, compiler-scheduled loads
  {
    h8 Av[4];
#pragma unroll
    for (int ntl = 0; ntl < 4; ++ntl)
      Av[ntl] = *(const h8*)&ws[(nbase + ntl * 16 + r) * PRS + g * 8];
    h8 pe[2];
#pragma unroll
    for (int t = 0; t < 2; ++t) pe[t] = *(const h8*)&X0[xr[t] + g * 8];
#pragma unroll
    for (int ntl = 0; ntl < 4; ++ntl) {
      f4 bini = *(const f4*)&BL[nbase + ntl * 16 + 4 * g];
      const int col = nbase + ntl * 16 + 4 * g;
#pragma unroll
      for (int t = 0; t < 2; ++t) {
        f4 acc = MFMA16(Av[ntl], pe[t], bini, 0, 0, 0);
        *(uint2*)&X1[xr[t] + col] =         // no relu on vde output
          make_uint2(pkrtz(acc[0], acc[1]), pkrtz(acc[2], acc[3]));
      }
    }
  }
  __syncthreads();   // X1 (vde out) published

  // ---- 11 full 128x128 layers, ping-pong: X1->X0->X1->...
  u32 vhp[2][4][2];            // captured vh: set at li==2, used at li==5
  h8 Ar0[4], Ar1[4], Ar2[4];   // 3-slot ring (48 VGPRs)
  LAYER(0, X1, X0);  LAYER(1, X0, X1);
  LAYER(2, X1, X0);  LAYER(3, X0, X1);   // li==2: vh capture + gather -> X0
  LAYER(4, X1, X0);  LAYER(5, X0, X1);
  LAYER(6, X1, X0);  LAYER(7, X0, X1);
  LAYER(8, X1, X0);  LAYER(9, X0, X1);
  LAYER(10, X1, X0);

  // ---- head_W2 (128 -> 4) + head_b2 from X0; compiler-scheduled weights
  if (cg == 0) {
    h8 x[2][4];
#pragma unroll
    for (int t = 0; t < 2; ++t)
#pragma unroll
      for (int ks = 0; ks < 4; ++ks)
        x[t][ks] = *(const h8*)&X0[xr[t] + ks * 32 + g * 8];
    const u16* wa = ws + WOFF + 11 * FULLT;
    f4 b2 = *(const f4*)&BL[1536 + 4 * g];   // g==0 lanes: real head_b2
    f4 acc[2] = {b2, b2};
#pragma unroll
    for (int ks = 0; ks < 4; ++ks) {
      h8 A = *(const h8*)&wa[ks * 512 + lane * 8];
#pragma unroll
      for (int t = 0; t < 2; ++t)
        acc[t] = MFMA16(A, x[t][ks], acc[t], 0, 0, 0);
    }
    if (g == 0) {                      // lane r holds pixel r's rgba contiguously
#pragma unroll
      for (int t = 0; t < 2; ++t)
        *(f4*)&out[(bpix + pbase + t * 16 + r) * 4] = acc[t];
    }
  }
}

// ---------------------------------------------------------------------------
extern "C" void kernel_launch(void* const* d_in, const int* in_sizes, int n_in,
                              void* d_out, int out_size, void* d_ws, size_t ws_size,
                              hipStream_t stream) {
  const int*   vert    = (const int*)  d_in[0];
  const float* bary    = (const float*)d_in[1];
  const float* view    = (const float*)d_in[2];
  const float* emb     = (const float*)d_in[3];
  const float* vde_W   = (const float*)d_in[4];
  const float* vde_b   = (const float*)d_in[5];
  const float* vh_W    = (const float*)d_in[6];
  const float* vh_b    = (const float*)d_in[7];
  const float* hid_W   = (const float*)d_in[8];
  const float* hid_b   = (const float*)d_in[9];
  const float* head_W0 = (const float*)d_in[10];
  const float* head_b0 = (const float*)d_in[11];
  const float* head_W1 = (const float*)d_in[12];
  const float* head_b1 = (const float*)d_in[13];
  const float* head_W2 = (const float*)d_in[14];
  const float* head_b2 = (const float*)d_in[15];
  u16* wsp = (u16*)d_ws;   // needs 403456 B

  rc_prep<<<788, 256, 0, stream>>>(vde_W, vh_W, hid_W, head_W0, head_W1, head_W2, wsp);
  rc_main<<<4096, 512, 0, stream>>>(vert, bary, view, emb, vde_b, vh_b, hid_b,
                                    head_b0, head_b1, head_b2, wsp, (float*)d_out);
}